// Round 5
// baseline (888.002 us; speedup 1.0000x reference)
//
#include <hip/hip_runtime.h>
#include <math.h>

#define Bsz 1024
#define Tt  128
#define Ff  32
#define Ee  16
#define Hh  20
#define Dd  4096
#define EPSc 1e-3f
#define LOG2E 1.4426950408889634f

// repacked fp32 weights per expert, gate-interleaved cols c = 4*u + g (g: i,f,g,o):
// K1p[32][80]@0, R1p[20][80]@2560, K2p[20][80]@4160, R2p[20][80]@5760,
// b1p[80]@7360, b2p[80]@7440  -> 7520 floats per expert
// i/f/o gate columns (g != 2) are pre-scaled by log2(e) so sigmoid uses exp2 directly.
#define PWE 7520

typedef __attribute__((ext_vector_type(8))) short bf16x8;
typedef __attribute__((ext_vector_type(4))) float f32x4;
typedef __attribute__((ext_vector_type(4))) unsigned int u32x4;

#define MFMA16(a,b,c) __builtin_amdgcn_mfma_f32_16x16x32_bf16(a, b, c, 0, 0, 0)

__device__ __forceinline__ float sig2(float z) {      // z already scaled by log2(e)
    return __builtin_amdgcn_rcpf(1.0f + __builtin_amdgcn_exp2f(-z));
}
__device__ __forceinline__ unsigned short bf16_rne(float f) {
    unsigned u = __float_as_uint(f);
    u += 0x7FFFu + ((u >> 16) & 1u);
    return (unsigned short)(u >> 16);
}
__device__ __forceinline__ float bf16_to_f(unsigned short h) {
    return __uint_as_float(((unsigned)h) << 16);
}
// split 2 floats into packed-bf16 hi word + packed-bf16 lo word, RNE both
// (identical numerics to bf16_rne path; v_cvt_pk_bf16_f32 is RNE).
__device__ __forceinline__ void cvt2(float f0, float f1, unsigned& hp, unsigned& lp) {
    asm("v_cvt_pk_bf16_f32 %0, %1, %2" : "=v"(hp) : "v"(f0), "v"(f1));
    float h0 = __uint_as_float(hp << 16);
    float h1 = __uint_as_float(hp & 0xFFFF0000u);
    asm("v_cvt_pk_bf16_f32 %0, %1, %2" : "=v"(lp) : "v"(f0 - h0), "v"(f1 - h1));
}

// ---------------------------------------------------------------- x prepass: BN + bf16 hi/lo split
__global__ void xpack_kernel(const float* __restrict__ x,
                             const float* __restrict__ gamma, const float* __restrict__ beta,
                             const float* __restrict__ mean,  const float* __restrict__ var,
                             unsigned short* __restrict__ xph, unsigned short* __restrict__ xpl)
{
    __shared__ float sc[Ff], sh[Ff];
    int tid = threadIdx.x;
    if (tid < Ff) {
        float s = gamma[tid] * rsqrtf(var[tid] + EPSc);
        sc[tid] = s;
        sh[tid] = beta[tid] - mean[tid] * s;
    }
    __syncthreads();
    int idx = blockIdx.x * 256 + tid;           // 0 .. 64*128*64-1
    int c   = idx >> 13;
    int rem = idx & 8191;
    int t   = rem >> 6;
    int l   = rem & 63;
    int q   = l >> 4, s = l & 15;
    const float* xr = x + ((size_t)(c * 16 + s) * Tt + t) * Ff + q * 8;
    float4 v0 = *(const float4*)xr;
    float4 v1 = *(const float4*)(xr + 4);
    float xv[8] = {v0.x, v0.y, v0.z, v0.w, v1.x, v1.y, v1.z, v1.w};
    bf16x8 hv, lv;
#pragma unroll
    for (int j = 0; j < 8; ++j) {
        int f = q * 8 + j;
        float xn_ = xv[j] * sc[f] + sh[f];
        unsigned short hi = bf16_rne(xn_);
        hv[j] = (short)hi;
        lv[j] = (short)bf16_rne(xn_ - bf16_to_f(hi));
    }
    *(bf16x8*)(xph + (size_t)idx * 8) = hv;
    *(bf16x8*)(xpl + (size_t)idx * 8) = lv;
}

// ---------------------------------------------------------------- weight repack (gate-interleave)
__global__ void repack2_kernel(const float* __restrict__ k1, const float* __restrict__ r1,
                               const float* __restrict__ b1, const float* __restrict__ k2,
                               const float* __restrict__ r2, const float* __restrict__ b2,
                               float* __restrict__ pw)
{
    int idx = blockIdx.x * blockDim.x + threadIdx.x;
    if (idx >= Ee * PWE) return;
    int e = idx / PWE;
    int o = idx % PWE;
    float v;
    int g;
    if (o < 7360) {
        int c = o % 80, u = c >> 2;
        g = c & 3;
        int co = g * 20 + u;
        if (o < 2560) {
            int kk = o / 80;
            v = k1[((size_t)e * Ff + kk) * 80 + co];
        } else if (o < 4160) {
            int kk = (o - 2560) / 80;
            v = r1[((size_t)e * Hh + kk) * 80 + co];
        } else if (o < 5760) {
            int kk = (o - 4160) / 80;
            v = k2[((size_t)e * Hh + kk) * 80 + co];
        } else {
            int kk = (o - 5760) / 80;
            v = r2[((size_t)e * Hh + kk) * 80 + co];
        }
    } else if (o < 7440) {
        int c = o - 7360, u = c >> 2;
        g = c & 3;
        v = b1[(size_t)e * 80 + g * 20 + u];
    } else {
        int c = o - 7440, u = c >> 2;
        g = c & 3;
        v = b2[(size_t)e * 80 + g * 20 + u];
    }
    if (g != 2) v *= LOG2E;     // sigmoid gates -> exp2 domain
    pw[idx] = v;
}

// ---------------------------------------------------------------- fused lstm + fc1
// 768 blocks x 256 thr, 3 blocks/CU (LDS-capped at 43KB; launch_bounds min 3 w/EU ->
// VGPR cap 170, current use 128). Round-robin dispatch puts blocks {i, i+256, i+512}
// on the same CU -> each CU runs 1 latency-bound LSTM block + 2 throughput fc1
// blocks; per SIMD: 1 LSTM wave + 2 fc1 waves (m114 co-scheduling, deeper TLP).
//
// LSTM: swapped-operand MFMA + permuted k-map; h fully register-resident (no LDS).
// fc1: 64x128 tile per block (512 blocks). A operand direct global->reg->cvt2,
// prefetched 1 step in regs. W double-buffered LDS (2x20KB), one barrier per
// 32-K step, W globals prefetched ~1 step ahead. W rows = 40 shorts (16B-aligned);
// 16B k-slots swizzled: phys = (logical + (row>>3) + (row>>5)) & 3 -- the (row>>5)
// term breaks the period-32 bank repeat that caused R4's 2^23 conflict cycles.
__global__ __launch_bounds__(256, 3) void fused_kernel(
    const unsigned short* __restrict__ xph, const unsigned short* __restrict__ xpl,
    const float* __restrict__ pw, const float* __restrict__ dw, const float* __restrict__ db,
    float* __restrict__ eo,
    const float* __restrict__ x, const float* __restrict__ W,
    const float* __restrict__ bias, float* __restrict__ C)
{
    __shared__ __align__(16) char smem[43008];

    if (blockIdx.x < 256) {
        // ================= LSTM path: wave w handles tile blockIdx.x*4+w =================
        const int l = threadIdx.x & 63;
        const int q = l >> 4, s = l & 15;
        const int tile = (blockIdx.x << 2) + (threadIdx.x >> 6);
        const int e = tile >> 6;
        const int c = tile & 63;
        const int b0 = c * 16;

        const float* Wm = pw + (size_t)e * PWE;
        bf16x8 K1h[5], K1l[5], R1h[5], R1l[5], K2h[5], K2l[5], R2h[5], R2l[5];
#pragma unroll
        for (int n = 0; n < 5; ++n) {
#pragma unroll
            for (int j = 0; j < 8; ++j) {
                int k8 = q * 8 + j;         // K1: x-feature k-map (32 features)
                int uk = 4 * j + q;         // R1/K2/R2: permuted h-unit k-map (j<5 valid)
                int cc = n * 16 + s;
                float wv_;
                unsigned short hi; float hf;
                wv_ = Wm[k8 * 80 + cc];
                hi = bf16_rne(wv_); hf = bf16_to_f(hi);
                K1h[n][j] = (short)hi; K1l[n][j] = (short)bf16_rne(wv_ - hf);
                wv_ = (j < 5) ? Wm[2560 + uk * 80 + cc] : 0.f;
                hi = bf16_rne(wv_); hf = bf16_to_f(hi);
                R1h[n][j] = (short)hi; R1l[n][j] = (short)bf16_rne(wv_ - hf);
                wv_ = (j < 5) ? Wm[4160 + uk * 80 + cc] : 0.f;
                hi = bf16_rne(wv_); hf = bf16_to_f(hi);
                K2h[n][j] = (short)hi; K2l[n][j] = (short)bf16_rne(wv_ - hf);
                wv_ = (j < 5) ? Wm[5760 + uk * 80 + cc] : 0.f;
                hi = bf16_rne(wv_); hf = bf16_to_f(hi);
                R2h[n][j] = (short)hi; R2l[n][j] = (short)bf16_rne(wv_ - hf);
            }
        }
        f32x4 bf1[5], bf2[5];
        float dwr[5];
#pragma unroll
        for (int n = 0; n < 5; ++n) {
            bf1[n] = *(const f32x4*)&Wm[7360 + n * 16 + 4 * q];
            bf2[n] = *(const f32x4*)&Wm[7440 + n * 16 + 4 * q];
            dwr[n] = dw[e * Hh + 4 * n + q];
        }

        float c1[5] = {0, 0, 0, 0, 0}, c2[5] = {0, 0, 0, 0, 0};
        float h2reg[5] = {0, 0, 0, 0, 0};

        const bf16x8 z8 = {0, 0, 0, 0, 0, 0, 0, 0};
        bf16x8 H1a = z8, H1b = z8, H2a = z8, H2b = z8;   // h[t-1] fragments, reg-resident

        const unsigned short* xbh = xph + (size_t)c * 65536 + l * 8;
        const unsigned short* xbl = xpl + (size_t)c * 65536 + l * 8;
        bf16x8 xch = *(const bf16x8*)xbh;
        bf16x8 xcl = *(const bf16x8*)xbl;

#pragma unroll 1
        for (int t = 0; t < Tt; ++t) {
            bf16x8 xnh = xch, xnl = xcl;
            if (t < Tt - 1) {       // prefetch t+1 (overlaps this step's compute)
                xnh = *(const bf16x8*)(xbh + (t + 1) * 512);
                xnl = *(const bf16x8*)(xbl + (t + 1) * 512);
            }

            // ---- layer 1: z^T = K1^T x^T + R1^T h1^T  (x first, fresh H1 last)
            f32x4 a1[5];
#pragma unroll
            for (int n = 0; n < 5; ++n) {
                f32x4 acc = bf1[n];
                acc = MFMA16(K1h[n], xch, acc);
                acc = MFMA16(K1l[n], xch, acc);
                acc = MFMA16(K1h[n], xcl, acc);
                acc = MFMA16(R1h[n], H1a, acc);
                acc = MFMA16(R1l[n], H1a, acc);
                acc = MFMA16(R1h[n], H1b, acc);
                a1[n] = acc;
            }
            {
                float hv[5];
#pragma unroll
                for (int n = 0; n < 5; ++n) {
                    float iv = sig2(a1[n][0]);
                    float fv = sig2(a1[n][1]);
                    float gv = fmaxf(a1[n][2], 0.f);
                    float ov = sig2(a1[n][3]);
                    c1[n] = fv * c1[n] + iv * gv;
                    hv[n] = ov * fmaxf(c1[n], 0.f);
                }
                unsigned h0, h1, h2, l0, l1, l2;
                cvt2(hv[0], hv[1], h0, l0);
                cvt2(hv[2], hv[3], h1, l1);
                cvt2(hv[4], 0.f,   h2, l2);
                u32x4 uh = {h0, h1, h2, 0u}, ul = {l0, l1, l2, 0u};
                H1a = __builtin_bit_cast(bf16x8, uh);
                H1b = __builtin_bit_cast(bf16x8, ul);
            }

            // ---- layer 2: stale H2 first, freshly-packed H1 last (cvt2 slack)
            f32x4 a2[5];
#pragma unroll
            for (int n = 0; n < 5; ++n) {
                f32x4 acc = bf2[n];
                acc = MFMA16(R2h[n], H2a, acc);
                acc = MFMA16(R2l[n], H2a, acc);
                acc = MFMA16(R2h[n], H2b, acc);
                acc = MFMA16(K2h[n], H1a, acc);
                acc = MFMA16(K2l[n], H1a, acc);
                acc = MFMA16(K2h[n], H1b, acc);
                a2[n] = acc;
            }
            {
                float hv[5];
#pragma unroll
                for (int n = 0; n < 5; ++n) {
                    float iv = sig2(a2[n][0]);
                    float fv = sig2(a2[n][1]);
                    float gv = fmaxf(a2[n][2], 0.f);
                    float ov = sig2(a2[n][3]);
                    c2[n] = fv * c2[n] + iv * gv;
                    float h = ov * fmaxf(c2[n], 0.f);
                    h2reg[n] = h;
                    hv[n] = h;
                }
                unsigned h0, h1, h2, l0, l1, l2;
                cvt2(hv[0], hv[1], h0, l0);
                cvt2(hv[2], hv[3], h1, l1);
                cvt2(hv[4], 0.f,   h2, l2);
                u32x4 uh = {h0, h1, h2, 0u}, ul = {l0, l1, l2, 0u};
                H2a = __builtin_bit_cast(bf16x8, uh);
                H2b = __builtin_bit_cast(bf16x8, ul);
            }

            xch = xnh; xcl = xnl;
        }

        float p = 0.f;
#pragma unroll
        for (int n = 0; n < 5; ++n) p += h2reg[n] * dwr[n];
        p += __shfl_xor(p, 16);
        p += __shfl_xor(p, 32);
        if (q == 0) eo[(size_t)e * Bsz + b0 + s] = db[e] + p;

    } else {
        // ================= fc1 path: 64x128 tile, A-direct + W-dbuf =================
        const int tid = threadIdx.x;
        const int wv = tid >> 6, l = tid & 63, q = l >> 4, s = l & 15;
        const int id = blockIdx.x - 256;                 // 0..511
        const int n0 = (id & 31) * 128, m0 = (id >> 5) * 64;
        const int wr = (wv & 1) * 32, wc = (wv >> 1) * 64;

        const int wn = tid & 127, wkq = tid >> 7;
        // physical slot for W stores: logical slots {2*wkq, 2*wkq+1}
        const int wrot = ((wn >> 3) + (wn >> 5)) & 3;
        const int ws0 = ((wkq * 2) + wrot) & 3;
        const int ws1 = ((wkq * 2 + 1) + wrot) & 3;

        const float* WG = W + (size_t)(wkq * 16) * Dd + n0 + wn;
        const float* Arow = x + (size_t)(m0 + wr + s) * Dd + q * 8;

        unsigned short* lds = (unsigned short*)smem;   // [2][ Wsh 5120 | Wsl 5120 ]

        f32x4 acc[2][4];
#pragma unroll
        for (int mt = 0; mt < 2; ++mt)
#pragma unroll
            for (int nt = 0; nt < 4; ++nt) acc[mt][nt] = (f32x4){0.f, 0.f, 0.f, 0.f};

        float wfp[16];
        float4 afc[4];

        {   // prologue: W k-step0 -> buf0; W k-step1 -> wfp; A k-step0 -> afc
            float w0[16];
#pragma unroll
            for (int i = 0; i < 16; ++i) w0[i] = WG[(size_t)i * Dd];
            uint4 h0, l0, h1, l1;
            cvt2(w0[0],  w0[1],  h0.x, l0.x); cvt2(w0[2],  w0[3],  h0.y, l0.y);
            cvt2(w0[4],  w0[5],  h0.z, l0.z); cvt2(w0[6],  w0[7],  h0.w, l0.w);
            cvt2(w0[8],  w0[9],  h1.x, l1.x); cvt2(w0[10], w0[11], h1.y, l1.y);
            cvt2(w0[12], w0[13], h1.z, l1.z); cvt2(w0[14], w0[15], h1.w, l1.w);
            *(uint4*)&lds[wn * 40 + ws0 * 8]          = h0;
            *(uint4*)&lds[5120 + wn * 40 + ws0 * 8]   = l0;
            *(uint4*)&lds[wn * 40 + ws1 * 8]          = h1;
            *(uint4*)&lds[5120 + wn * 40 + ws1 * 8]   = l1;
#pragma unroll
            for (int i = 0; i < 16; ++i) wfp[i] = WG[(size_t)(32 + i) * Dd];
#pragma unroll
            for (int mt = 0; mt < 2; ++mt) {
                afc[mt * 2]     = *(const float4*)(Arow + (size_t)mt * 16 * Dd);
                afc[mt * 2 + 1] = *(const float4*)(Arow + (size_t)mt * 16 * Dd + 4);
            }
            __syncthreads();
        }

#pragma unroll 1
        for (int it = 0; it < 128; ++it) {
            const int k0 = it * 32;
            unsigned short* cb = lds + (it & 1) * 10240;        // compute buffer
            unsigned short* sb = lds + ((it & 1) ^ 1) * 10240;  // store buffer

            // phase 1: store W(k-step it+1) from wfp
            if (it < 127) {
                uint4 h0, l0, h1, l1;
                cvt2(wfp[0],  wfp[1],  h0.x, l0.x); cvt2(wfp[2],  wfp[3],  h0.y, l0.y);
                cvt2(wfp[4],  wfp[5],  h0.z, l0.z); cvt2(wfp[6],  wfp[7],  h0.w, l0.w);
                cvt2(wfp[8],  wfp[9],  h1.x, l1.x); cvt2(wfp[10], wfp[11], h1.y, l1.y);
                cvt2(wfp[12], wfp[13], h1.z, l1.z); cvt2(wfp[14], wfp[15], h1.w, l1.w);
                *(uint4*)&sb[wn * 40 + ws0 * 8]        = h0;
                *(uint4*)&sb[5120 + wn * 40 + ws0 * 8] = l0;
                *(uint4*)&sb[wn * 40 + ws1 * 8]        = h1;
                *(uint4*)&sb[5120 + wn * 40 + ws1 * 8] = l1;
            }

            // phase 2: issue W global loads for k-step it+2
            {
                const int kW = (it + 2 < 128) ? k0 + 64 : k0;
#pragma unroll
                for (int i = 0; i < 16; ++i) wfp[i] = WG[(size_t)(kW + i) * Dd];
            }

            // phase 3: W fragments from compute buffer (slot-swizzled)
            bf16x8 Wfh[4], Wfl[4];
#pragma unroll
            for (int nt = 0; nt < 4; ++nt) {
                const int row = wc + nt * 16 + s;
                const int ps = (q + ((row >> 3) + (row >> 5))) & 3;
                Wfh[nt] = *(bf16x8*)&cb[row * 40 + ps * 8];
                Wfl[nt] = *(bf16x8*)&cb[5120 + row * 40 + ps * 8];
            }

            // phase 4: A fragments from prefetched regs; issue A loads for it+1
            bf16x8 Afh[2], Afl[2];
#pragma unroll
            for (int mt = 0; mt < 2; ++mt) {
                uint4 uh, ul;
                cvt2(afc[mt * 2].x,     afc[mt * 2].y,     uh.x, ul.x);
                cvt2(afc[mt * 2].z,     afc[mt * 2].w,     uh.y, ul.y);
                cvt2(afc[mt * 2 + 1].x, afc[mt * 2 + 1].y, uh.z, ul.z);
                cvt2(afc[mt * 2 + 1].z, afc[mt * 2 + 1].w, uh.w, ul.w);
                Afh[mt] = __builtin_bit_cast(bf16x8, uh);
                Afl[mt] = __builtin_bit_cast(bf16x8, ul);
            }
            {
                const int kA = (it + 1 < 128) ? k0 + 32 : k0;
#pragma unroll
                for (int mt = 0; mt < 2; ++mt) {
                    afc[mt * 2]     = *(const float4*)(Arow + (size_t)mt * 16 * Dd + kA);
                    afc[mt * 2 + 1] = *(const float4*)(Arow + (size_t)mt * 16 * Dd + kA + 4);
                }
            }

            // phase 5: MFMA
#pragma unroll
            for (int mt = 0; mt < 2; ++mt)
#pragma unroll
                for (int nt = 0; nt < 4; ++nt) {
                    f32x4 a = acc[mt][nt];
                    a = MFMA16(Afl[mt], Wfh[nt], a);
                    a = MFMA16(Afh[mt], Wfl[nt], a);
                    a = MFMA16(Afh[mt], Wfh[nt], a);
                    acc[mt][nt] = a;
                }

            // phase 6: one barrier per step
            __syncthreads();
        }

#pragma unroll
        for (int nt = 0; nt < 4; ++nt) {
            float bv = bias[n0 + wc + nt * 16 + s];
#pragma unroll
            for (int mt = 0; mt < 2; ++mt)
#pragma unroll
                for (int r = 0; r < 4; ++r) {
                    int m = m0 + wr + mt * 16 + q * 4 + r;
                    C[(size_t)m * Dd + n0 + wc + nt * 16 + s] = fmaxf(acc[mt][nt][r] + bv, 0.f);
                }
        }
    }
}

// ---------------------------------------------------------------- gate: softmax(g @ gate_w + gb) + combine
// 4 batch rows per block (256 blocks): gate_w vectors loaded once, reused x4
// -> gate_w L2/L3 traffic 256MB -> 64MB.
__global__ __launch_bounds__(256) void gate_kernel(const float* __restrict__ g,
                                                   const float* __restrict__ gw,
                                                   const float* __restrict__ gb,
                                                   const float* __restrict__ eo,
                                                   float* __restrict__ out)
{
    int b0 = blockIdx.x * 4;
    int tid = threadIdx.x;
    int lane = tid & 63;
    int wv = tid >> 6;

    float acc[4][16];
#pragma unroll
    for (int bb = 0; bb < 4; ++bb)
#pragma unroll
        for (int j = 0; j < 16; ++j) acc[bb][j] = 0.f;

    const float* g0 = g + (size_t)b0 * Dd;
#pragma unroll
    for (int it = 0; it < Dd / 256; ++it) {
        int d = tid + it * 256;
        const float4* wr_ = (const float4*)(gw + (size_t)d * 16);
        float4 w0 = wr_[0], w1 = wr_[1], w2 = wr_[2], w3 = wr_[3];
        float gv[4];
#pragma unroll
        for (int bb = 0; bb < 4; ++bb) gv[bb] = g0[(size_t)bb * Dd + d];
#pragma unroll
        for (int bb = 0; bb < 4; ++bb) {
            float v = gv[bb];
            acc[bb][0]  += v * w0.x;  acc[bb][1]  += v * w0.y;
            acc[bb][2]  += v * w0.z;  acc[bb][3]  += v * w0.w;
            acc[bb][4]  += v * w1.x;  acc[bb][5]  += v * w1.y;
            acc[bb][6]  += v * w1.z;  acc[bb][7]  += v * w1.w;
            acc[bb][8]  += v * w2.x;  acc[bb][9]  += v * w2.y;
            acc[bb][10] += v * w2.z;  acc[bb][11] += v * w2.w;
            acc[bb][12] += v * w3.x;  acc[bb][13] += v * w3.y;
            acc[bb][14] += v * w3.z;  acc[bb][15] += v * w3.w;
        }
    }

    __shared__ float red[4][4][16];     // [wave][bb][j]
    __shared__ float logits[4][16];
#pragma unroll
    for (int bb = 0; bb < 4; ++bb)
#pragma unroll
        for (int j = 0; j < 16; ++j) {
            float v = acc[bb][j];
#pragma unroll
            for (int m = 32; m >= 1; m >>= 1) v += __shfl_xor(v, m);
            if (lane == 0) red[wv][bb][j] = v;
        }
    __syncthreads();
    if (tid < 64) {
        int bb = tid >> 4, j = tid & 15;
        logits[bb][j] = gb[j] + red[0][bb][j] + red[1][bb][j] + red[2][bb][j] + red[3][bb][j];
    }
    __syncthreads();
    if (tid < 4) {
        int b = b0 + tid;
        float m = logits[tid][0];
#pragma unroll
        for (int j = 1; j < 16; ++j) m = fmaxf(m, logits[tid][j]);
        float ex[16], ssum = 0.f;
#pragma unroll
        for (int j = 0; j < 16; ++j) { ex[j] = __expf(logits[tid][j] - m); ssum += ex[j]; }
        float inv = 1.f / ssum;
        float o = 0.f;
#pragma unroll
        for (int j = 0; j < 16; ++j) o += ex[j] * inv * eo[(size_t)j * Bsz + b];
        out[b] = o;
    }
}

// ----------------------------------------------------------------
extern "C" void kernel_launch(void* const* d_in, const int* in_sizes, int n_in,
                              void* d_out, int out_size, void* d_ws, size_t ws_size,
                              hipStream_t stream)
{
    const float* x     = (const float*)d_in[0];
    const float* gamma = (const float*)d_in[1];
    const float* beta  = (const float*)d_in[2];
    const float* mean  = (const float*)d_in[3];
    const float* var   = (const float*)d_in[4];
    const float* k1    = (const float*)d_in[5];
    const float* r1    = (const float*)d_in[6];
    const float* b1    = (const float*)d_in[7];
    const float* k2    = (const float*)d_in[8];
    const float* r2    = (const float*)d_in[9];
    const float* b2    = (const float*)d_in[10];
    const float* dw    = (const float*)d_in[11];
    const float* db    = (const float*)d_in[12];
    const float* fc1w  = (const float*)d_in[13];
    const float* fc1b  = (const float*)d_in[14];
    const float* gw    = (const float*)d_in[15];
    const float* gb    = (const float*)d_in[16];
    float* out = (float*)d_out;

    // workspace: 33.1 MB (<= previously-proven 34.2 MB footprint)
    float* g = (float*)d_ws;                                        // 4,194,304 f (16 MB)
    unsigned short* xph = (unsigned short*)(g + (size_t)Bsz * Dd);  // 8 MB
    unsigned short* xpl = xph + (size_t)Bsz * Dd / 2 * 2;           // 8 MB
    float* pw  = (float*)(xpl + (size_t)4194304);                   // 120,320 f
    float* eo  = pw + (size_t)Ee * PWE;                             // 16,384 f

    xpack_kernel<<<2048, 256, 0, stream>>>(x, gamma, beta, mean, var, xph, xpl);
    repack2_kernel<<<(Ee * PWE + 255) / 256, 256, 0, stream>>>(k1, r1, b1, k2, r2, b2, pw);
    fused_kernel<<<768, 256, 0, stream>>>(xph, xpl, pw, dw, db, eo, x, fc1w, fc1b, g);
    gate_kernel<<<Bsz / 4, 256, 0, stream>>>(g, gw, gb, eo, out);
}

// Round 6
// 747.061 us; speedup vs baseline: 1.1887x; 1.1887x over previous
//
#include <hip/hip_runtime.h>
#include <math.h>

#define Bsz 1024
#define Tt  128
#define Ff  32
#define Ee  16
#define Hh  20
#define Dd  4096
#define EPSc 1e-3f
#define LOG2E 1.4426950408889634f

// repacked fp32 weights per expert, gate-interleaved cols c = 4*u + g (g: i,f,g,o):
// K1p[32][80]@0, R1p[20][80]@2560, K2p[20][80]@4160, R2p[20][80]@5760,
// b1p[80]@7360, b2p[80]@7440  -> 7520 floats per expert
// i/f/o gate columns (g != 2) are pre-scaled by log2(e) so sigmoid uses exp2 directly.
#define PWE 7520

typedef __attribute__((ext_vector_type(8))) short bf16x8;
typedef __attribute__((ext_vector_type(4))) float f32x4;
typedef __attribute__((ext_vector_type(4))) unsigned int u32x4;

#define MFMA16(a,b,c) __builtin_amdgcn_mfma_f32_16x16x32_bf16(a, b, c, 0, 0, 0)

__device__ __forceinline__ float sig2(float z) {      // z already scaled by log2(e)
    return __builtin_amdgcn_rcpf(1.0f + __builtin_amdgcn_exp2f(-z));
}
__device__ __forceinline__ unsigned short bf16_rne(float f) {
    unsigned u = __float_as_uint(f);
    u += 0x7FFFu + ((u >> 16) & 1u);
    return (unsigned short)(u >> 16);
}
__device__ __forceinline__ float bf16_to_f(unsigned short h) {
    return __uint_as_float(((unsigned)h) << 16);
}
// split 2 floats into packed-bf16 hi word + packed-bf16 lo word, RNE both
// (identical numerics to bf16_rne path; v_cvt_pk_bf16_f32 is RNE).
__device__ __forceinline__ void cvt2(float f0, float f1, unsigned& hp, unsigned& lp) {
    asm("v_cvt_pk_bf16_f32 %0, %1, %2" : "=v"(hp) : "v"(f0), "v"(f1));
    float h0 = __uint_as_float(hp << 16);
    float h1 = __uint_as_float(hp & 0xFFFF0000u);
    asm("v_cvt_pk_bf16_f32 %0, %1, %2" : "=v"(lp) : "v"(f0 - h0), "v"(f1 - h1));
}

// ---------------------------------------------------------------- x prepass: BN + bf16 hi/lo split
__global__ void xpack_kernel(const float* __restrict__ x,
                             const float* __restrict__ gamma, const float* __restrict__ beta,
                             const float* __restrict__ mean,  const float* __restrict__ var,
                             unsigned short* __restrict__ xph, unsigned short* __restrict__ xpl)
{
    __shared__ float sc[Ff], sh[Ff];
    int tid = threadIdx.x;
    if (tid < Ff) {
        float s = gamma[tid] * rsqrtf(var[tid] + EPSc);
        sc[tid] = s;
        sh[tid] = beta[tid] - mean[tid] * s;
    }
    __syncthreads();
    int idx = blockIdx.x * 256 + tid;           // 0 .. 64*128*64-1
    int c   = idx >> 13;
    int rem = idx & 8191;
    int t   = rem >> 6;
    int l   = rem & 63;
    int q   = l >> 4, s = l & 15;
    const float* xr = x + ((size_t)(c * 16 + s) * Tt + t) * Ff + q * 8;
    float4 v0 = *(const float4*)xr;
    float4 v1 = *(const float4*)(xr + 4);
    float xv[8] = {v0.x, v0.y, v0.z, v0.w, v1.x, v1.y, v1.z, v1.w};
    bf16x8 hv, lv;
#pragma unroll
    for (int j = 0; j < 8; ++j) {
        int f = q * 8 + j;
        float xn_ = xv[j] * sc[f] + sh[f];
        unsigned short hi = bf16_rne(xn_);
        hv[j] = (short)hi;
        lv[j] = (short)bf16_rne(xn_ - bf16_to_f(hi));
    }
    *(bf16x8*)(xph + (size_t)idx * 8) = hv;
    *(bf16x8*)(xpl + (size_t)idx * 8) = lv;
}

// ---------------------------------------------------------------- weight repack (gate-interleave)
__global__ void repack2_kernel(const float* __restrict__ k1, const float* __restrict__ r1,
                               const float* __restrict__ b1, const float* __restrict__ k2,
                               const float* __restrict__ r2, const float* __restrict__ b2,
                               float* __restrict__ pw)
{
    int idx = blockIdx.x * blockDim.x + threadIdx.x;
    if (idx >= Ee * PWE) return;
    int e = idx / PWE;
    int o = idx % PWE;
    float v;
    int g;
    if (o < 7360) {
        int c = o % 80, u = c >> 2;
        g = c & 3;
        int co = g * 20 + u;
        if (o < 2560) {
            int kk = o / 80;
            v = k1[((size_t)e * Ff + kk) * 80 + co];
        } else if (o < 4160) {
            int kk = (o - 2560) / 80;
            v = r1[((size_t)e * Hh + kk) * 80 + co];
        } else if (o < 5760) {
            int kk = (o - 4160) / 80;
            v = k2[((size_t)e * Hh + kk) * 80 + co];
        } else {
            int kk = (o - 5760) / 80;
            v = r2[((size_t)e * Hh + kk) * 80 + co];
        }
    } else if (o < 7440) {
        int c = o - 7360, u = c >> 2;
        g = c & 3;
        v = b1[(size_t)e * 80 + g * 20 + u];
    } else {
        int c = o - 7440, u = c >> 2;
        g = c & 3;
        v = b2[(size_t)e * 80 + g * 20 + u];
    }
    if (g != 2) v *= LOG2E;     // sigmoid gates -> exp2 domain
    pw[idx] = v;
}

// ---------------------------------------------------------------- fused lstm + fc1
// 512 blocks x 256 thr, 2 blocks/CU (R4-proven structure; R5's 3-block variant never
// achieved residency and quadrupled L2-miss traffic -- reverted). Blocks i and i+256
// land on the same CU; selector blockIdx.x<256 pairs 1 LSTM block + 1 fc1 block/CU.
//
// LSTM: swapped-operand MFMA + permuted k-map; h fully register-resident (no LDS).
// fc1: 128x128 tile. A direct global->reg->cvt2 (1-step reg prefetch). W double-
// buffered LDS, one barrier per 32-K step, W globals prefetched via wfp[2] ping-pong
// with a 2-ITERATION load->store gap (~1300cy > 900cy HBM worst-case latency).
// W rows padded to 44 shorts (88B): store start-banks 22*wn mod 32 cover all 16 even
// positions -> 4-way (was 8-way at stride 40). 16B alignment preserved.
__global__ __launch_bounds__(256, 2) void fused_kernel(
    const unsigned short* __restrict__ xph, const unsigned short* __restrict__ xpl,
    const float* __restrict__ pw, const float* __restrict__ dw, const float* __restrict__ db,
    float* __restrict__ eo,
    const float* __restrict__ x, const float* __restrict__ W,
    const float* __restrict__ bias, float* __restrict__ C)
{
    __shared__ __align__(16) char smem[45056];   // 2 x (Wsh 5632 + Wsl 5632 shorts)

    if (blockIdx.x < 256) {
        // ================= LSTM path: wave w handles tile blockIdx.x*4+w =================
        const int l = threadIdx.x & 63;
        const int q = l >> 4, s = l & 15;
        const int tile = (blockIdx.x << 2) + (threadIdx.x >> 6);
        const int e = tile >> 6;
        const int c = tile & 63;
        const int b0 = c * 16;

        const float* Wm = pw + (size_t)e * PWE;
        bf16x8 K1h[5], K1l[5], R1h[5], R1l[5], K2h[5], K2l[5], R2h[5], R2l[5];
#pragma unroll
        for (int n = 0; n < 5; ++n) {
#pragma unroll
            for (int j = 0; j < 8; ++j) {
                int k8 = q * 8 + j;         // K1: x-feature k-map (32 features)
                int uk = 4 * j + q;         // R1/K2/R2: permuted h-unit k-map (j<5 valid)
                int cc = n * 16 + s;
                float wv_;
                unsigned short hi; float hf;
                wv_ = Wm[k8 * 80 + cc];
                hi = bf16_rne(wv_); hf = bf16_to_f(hi);
                K1h[n][j] = (short)hi; K1l[n][j] = (short)bf16_rne(wv_ - hf);
                wv_ = (j < 5) ? Wm[2560 + uk * 80 + cc] : 0.f;
                hi = bf16_rne(wv_); hf = bf16_to_f(hi);
                R1h[n][j] = (short)hi; R1l[n][j] = (short)bf16_rne(wv_ - hf);
                wv_ = (j < 5) ? Wm[4160 + uk * 80 + cc] : 0.f;
                hi = bf16_rne(wv_); hf = bf16_to_f(hi);
                K2h[n][j] = (short)hi; K2l[n][j] = (short)bf16_rne(wv_ - hf);
                wv_ = (j < 5) ? Wm[5760 + uk * 80 + cc] : 0.f;
                hi = bf16_rne(wv_); hf = bf16_to_f(hi);
                R2h[n][j] = (short)hi; R2l[n][j] = (short)bf16_rne(wv_ - hf);
            }
        }
        f32x4 bf1[5], bf2[5];
        float dwr[5];
#pragma unroll
        for (int n = 0; n < 5; ++n) {
            bf1[n] = *(const f32x4*)&Wm[7360 + n * 16 + 4 * q];
            bf2[n] = *(const f32x4*)&Wm[7440 + n * 16 + 4 * q];
            dwr[n] = dw[e * Hh + 4 * n + q];
        }

        float c1[5] = {0, 0, 0, 0, 0}, c2[5] = {0, 0, 0, 0, 0};
        float h2reg[5] = {0, 0, 0, 0, 0};

        const bf16x8 z8 = {0, 0, 0, 0, 0, 0, 0, 0};
        bf16x8 H1a = z8, H1b = z8, H2a = z8, H2b = z8;   // h[t-1] fragments, reg-resident

        const unsigned short* xbh = xph + (size_t)c * 65536 + l * 8;
        const unsigned short* xbl = xpl + (size_t)c * 65536 + l * 8;
        bf16x8 xch = *(const bf16x8*)xbh;
        bf16x8 xcl = *(const bf16x8*)xbl;

#pragma unroll 1
        for (int t = 0; t < Tt; ++t) {
            bf16x8 xnh = xch, xnl = xcl;
            if (t < Tt - 1) {       // prefetch t+1 (overlaps this step's compute)
                xnh = *(const bf16x8*)(xbh + (t + 1) * 512);
                xnl = *(const bf16x8*)(xbl + (t + 1) * 512);
            }

            // ---- layer 1: z^T = K1^T x^T + R1^T h1^T  (x first, fresh H1 last)
            f32x4 a1[5];
#pragma unroll
            for (int n = 0; n < 5; ++n) {
                f32x4 acc = bf1[n];
                acc = MFMA16(K1h[n], xch, acc);
                acc = MFMA16(K1l[n], xch, acc);
                acc = MFMA16(K1h[n], xcl, acc);
                acc = MFMA16(R1h[n], H1a, acc);
                acc = MFMA16(R1l[n], H1a, acc);
                acc = MFMA16(R1h[n], H1b, acc);
                a1[n] = acc;
            }
            {
                float hv[5];
#pragma unroll
                for (int n = 0; n < 5; ++n) {
                    float iv = sig2(a1[n][0]);
                    float fv = sig2(a1[n][1]);
                    float gv = fmaxf(a1[n][2], 0.f);
                    float ov = sig2(a1[n][3]);
                    c1[n] = fv * c1[n] + iv * gv;
                    hv[n] = ov * fmaxf(c1[n], 0.f);
                }
                unsigned h0, h1, h2, l0, l1, l2;
                cvt2(hv[0], hv[1], h0, l0);
                cvt2(hv[2], hv[3], h1, l1);
                cvt2(hv[4], 0.f,   h2, l2);
                u32x4 uh = {h0, h1, h2, 0u}, ul = {l0, l1, l2, 0u};
                H1a = __builtin_bit_cast(bf16x8, uh);
                H1b = __builtin_bit_cast(bf16x8, ul);
            }

            // ---- layer 2: stale H2 first, freshly-packed H1 last (cvt2 slack)
            f32x4 a2[5];
#pragma unroll
            for (int n = 0; n < 5; ++n) {
                f32x4 acc = bf2[n];
                acc = MFMA16(R2h[n], H2a, acc);
                acc = MFMA16(R2l[n], H2a, acc);
                acc = MFMA16(R2h[n], H2b, acc);
                acc = MFMA16(K2h[n], H1a, acc);
                acc = MFMA16(K2l[n], H1a, acc);
                acc = MFMA16(K2h[n], H1b, acc);
                a2[n] = acc;
            }
            {
                float hv[5];
#pragma unroll
                for (int n = 0; n < 5; ++n) {
                    float iv = sig2(a2[n][0]);
                    float fv = sig2(a2[n][1]);
                    float gv = fmaxf(a2[n][2], 0.f);
                    float ov = sig2(a2[n][3]);
                    c2[n] = fv * c2[n] + iv * gv;
                    float h = ov * fmaxf(c2[n], 0.f);
                    h2reg[n] = h;
                    hv[n] = h;
                }
                unsigned h0, h1, h2, l0, l1, l2;
                cvt2(hv[0], hv[1], h0, l0);
                cvt2(hv[2], hv[3], h1, l1);
                cvt2(hv[4], 0.f,   h2, l2);
                u32x4 uh = {h0, h1, h2, 0u}, ul = {l0, l1, l2, 0u};
                H2a = __builtin_bit_cast(bf16x8, uh);
                H2b = __builtin_bit_cast(bf16x8, ul);
            }

            xch = xnh; xcl = xnl;
        }

        float p = 0.f;
#pragma unroll
        for (int n = 0; n < 5; ++n) p += h2reg[n] * dwr[n];
        p += __shfl_xor(p, 16);
        p += __shfl_xor(p, 32);
        if (q == 0) eo[(size_t)e * Bsz + b0 + s] = db[e] + p;

    } else {
        // ================= fc1 path: 128x128, A-direct + W-dbuf =================
        const int tid = threadIdx.x;
        const int wv = tid >> 6, l = tid & 63, q = l >> 4, s = l & 15;
        const int id = blockIdx.x & 255;
        const int n0 = (id & 31) * 128, m0 = (id >> 5) * 128;
        const int wr = (wv & 1) * 64, wc = (wv >> 1) * 64;

        const int wn = tid & 127, wkq = tid >> 7;
        // physical slot for W stores: logical slots {2*wkq, 2*wkq+1}
        const int wrot = ((wn >> 3) + (wn >> 5)) & 3;
        const int ws0 = ((wkq * 2) + wrot) & 3;
        const int ws1 = ((wkq * 2 + 1) + wrot) & 3;

        const float* WG = W + (size_t)(wkq * 16) * Dd + n0 + wn;
        const float* Arow = x + (size_t)(m0 + wr + s) * Dd + q * 8;

        unsigned short* lds = (unsigned short*)smem;   // [2][ Wsh 5632 | Wsl 5632 ] (44/row)

        f32x4 acc[4][4];
#pragma unroll
        for (int mt = 0; mt < 4; ++mt)
#pragma unroll
            for (int nt = 0; nt < 4; ++nt) acc[mt][nt] = (f32x4){0.f, 0.f, 0.f, 0.f};

        float wfp[2][16];
        float4 afc[8];

        {   // prologue: W step0 -> buf0; W step1 -> wfp[1]; W step2 -> wfp[0]; A step0 -> afc
            float w0[16];
#pragma unroll
            for (int i = 0; i < 16; ++i) w0[i] = WG[(size_t)i * Dd];
            uint4 h0, l0, h1, l1;
            cvt2(w0[0],  w0[1],  h0.x, l0.x); cvt2(w0[2],  w0[3],  h0.y, l0.y);
            cvt2(w0[4],  w0[5],  h0.z, l0.z); cvt2(w0[6],  w0[7],  h0.w, l0.w);
            cvt2(w0[8],  w0[9],  h1.x, l1.x); cvt2(w0[10], w0[11], h1.y, l1.y);
            cvt2(w0[12], w0[13], h1.z, l1.z); cvt2(w0[14], w0[15], h1.w, l1.w);
            *(uint4*)&lds[wn * 44 + ws0 * 8]          = h0;
            *(uint4*)&lds[5632 + wn * 44 + ws0 * 8]   = l0;
            *(uint4*)&lds[wn * 44 + ws1 * 8]          = h1;
            *(uint4*)&lds[5632 + wn * 44 + ws1 * 8]   = l1;
#pragma unroll
            for (int i = 0; i < 16; ++i) wfp[1][i] = WG[(size_t)(32 + i) * Dd];
#pragma unroll
            for (int i = 0; i < 16; ++i) wfp[0][i] = WG[(size_t)(64 + i) * Dd];
#pragma unroll
            for (int mt = 0; mt < 4; ++mt) {
                afc[mt * 2]     = *(const float4*)(Arow + (size_t)mt * 16 * Dd);
                afc[mt * 2 + 1] = *(const float4*)(Arow + (size_t)mt * 16 * Dd + 4);
            }
            __syncthreads();
        }

#pragma unroll 1
        for (int it = 0; it < 128; ++it) {
            const int k0 = it * 32;
            unsigned short* cb = lds + (it & 1) * 11264;        // compute buffer (step it)
            unsigned short* sb = lds + ((it & 1) ^ 1) * 11264;  // store buffer (step it+1)
            float* wcur = wfp[(it + 1) & 1];                    // holds W step it+1

            // phase 1: store W(step it+1) -> sb (loaded 2 iterations ago)
            if (it < 127) {
                uint4 h0, l0, h1, l1;
                cvt2(wcur[0],  wcur[1],  h0.x, l0.x); cvt2(wcur[2],  wcur[3],  h0.y, l0.y);
                cvt2(wcur[4],  wcur[5],  h0.z, l0.z); cvt2(wcur[6],  wcur[7],  h0.w, l0.w);
                cvt2(wcur[8],  wcur[9],  h1.x, l1.x); cvt2(wcur[10], wcur[11], h1.y, l1.y);
                cvt2(wcur[12], wcur[13], h1.z, l1.z); cvt2(wcur[14], wcur[15], h1.w, l1.w);
                *(uint4*)&sb[wn * 44 + ws0 * 8]        = h0;
                *(uint4*)&sb[5632 + wn * 44 + ws0 * 8] = l0;
                *(uint4*)&sb[wn * 44 + ws1 * 8]        = h1;
                *(uint4*)&sb[5632 + wn * 44 + ws1 * 8] = l1;
            }

            // phase 2: issue W global loads for step it+3 into the just-freed buffer
            {
                const int kW = (it + 3 < 128) ? k0 + 96 : k0;
#pragma unroll
                for (int i = 0; i < 16; ++i) wcur[i] = WG[(size_t)(kW + i) * Dd];
            }

            // phase 3: W fragments from compute buffer (slot-swizzled)
            bf16x8 Wfh[4], Wfl[4];
#pragma unroll
            for (int nt = 0; nt < 4; ++nt) {
                const int row = wc + nt * 16 + s;
                const int ps = (q + ((row >> 3) + (row >> 5))) & 3;
                Wfh[nt] = *(bf16x8*)&cb[row * 44 + ps * 8];
                Wfl[nt] = *(bf16x8*)&cb[5632 + row * 44 + ps * 8];
            }

            // phase 4: A fragments from prefetched regs; issue A loads for it+1
            bf16x8 Afh[4], Afl[4];
#pragma unroll
            for (int mt = 0; mt < 4; ++mt) {
                uint4 uh, ul;
                cvt2(afc[mt * 2].x,     afc[mt * 2].y,     uh.x, ul.x);
                cvt2(afc[mt * 2].z,     afc[mt * 2].w,     uh.y, ul.y);
                cvt2(afc[mt * 2 + 1].x, afc[mt * 2 + 1].y, uh.z, ul.z);
                cvt2(afc[mt * 2 + 1].z, afc[mt * 2 + 1].w, uh.w, ul.w);
                Afh[mt] = __builtin_bit_cast(bf16x8, uh);
                Afl[mt] = __builtin_bit_cast(bf16x8, ul);
            }
            {
                const int kA = (it + 1 < 128) ? k0 + 32 : k0;
#pragma unroll
                for (int mt = 0; mt < 4; ++mt) {
                    afc[mt * 2]     = *(const float4*)(Arow + (size_t)mt * 16 * Dd + kA);
                    afc[mt * 2 + 1] = *(const float4*)(Arow + (size_t)mt * 16 * Dd + kA + 4);
                }
            }

            // phase 5: MFMA
#pragma unroll
            for (int mt = 0; mt < 4; ++mt)
#pragma unroll
                for (int nt = 0; nt < 4; ++nt) {
                    f32x4 a = acc[mt][nt];
                    a = MFMA16(Afl[mt], Wfh[nt], a);
                    a = MFMA16(Afh[mt], Wfl[nt], a);
                    a = MFMA16(Afh[mt], Wfh[nt], a);
                    acc[mt][nt] = a;
                }

            // phase 6: one barrier per step
            __syncthreads();
        }

#pragma unroll
        for (int nt = 0; nt < 4; ++nt) {
            float bv = bias[n0 + wc + nt * 16 + s];
#pragma unroll
            for (int mt = 0; mt < 4; ++mt)
#pragma unroll
                for (int r = 0; r < 4; ++r) {
                    int m = m0 + wr + mt * 16 + q * 4 + r;
                    C[(size_t)m * Dd + n0 + wc + nt * 16 + s] = fmaxf(acc[mt][nt][r] + bv, 0.f);
                }
        }
    }
}

// ---------------------------------------------------------------- gate: softmax(g @ gate_w + gb) + combine
// 4 batch rows per block (256 blocks): gate_w vectors loaded once, reused x4
// -> gate_w L2/L3 traffic 256MB -> 64MB.
__global__ __launch_bounds__(256) void gate_kernel(const float* __restrict__ g,
                                                   const float* __restrict__ gw,
                                                   const float* __restrict__ gb,
                                                   const float* __restrict__ eo,
                                                   float* __restrict__ out)
{
    int b0 = blockIdx.x * 4;
    int tid = threadIdx.x;
    int lane = tid & 63;
    int wv = tid >> 6;

    float acc[4][16];
#pragma unroll
    for (int bb = 0; bb < 4; ++bb)
#pragma unroll
        for (int j = 0; j < 16; ++j) acc[bb][j] = 0.f;

    const float* g0 = g + (size_t)b0 * Dd;
#pragma unroll
    for (int it = 0; it < Dd / 256; ++it) {
        int d = tid + it * 256;
        const float4* wr_ = (const float4*)(gw + (size_t)d * 16);
        float4 w0 = wr_[0], w1 = wr_[1], w2 = wr_[2], w3 = wr_[3];
        float gv[4];
#pragma unroll
        for (int bb = 0; bb < 4; ++bb) gv[bb] = g0[(size_t)bb * Dd + d];
#pragma unroll
        for (int bb = 0; bb < 4; ++bb) {
            float v = gv[bb];
            acc[bb][0]  += v * w0.x;  acc[bb][1]  += v * w0.y;
            acc[bb][2]  += v * w0.z;  acc[bb][3]  += v * w0.w;
            acc[bb][4]  += v * w1.x;  acc[bb][5]  += v * w1.y;
            acc[bb][6]  += v * w1.z;  acc[bb][7]  += v * w1.w;
            acc[bb][8]  += v * w2.x;  acc[bb][9]  += v * w2.y;
            acc[bb][10] += v * w2.z;  acc[bb][11] += v * w2.w;
            acc[bb][12] += v * w3.x;  acc[bb][13] += v * w3.y;
            acc[bb][14] += v * w3.z;  acc[bb][15] += v * w3.w;
        }
    }

    __shared__ float red[4][4][16];     // [wave][bb][j]
    __shared__ float logits[4][16];
#pragma unroll
    for (int bb = 0; bb < 4; ++bb)
#pragma unroll
        for (int j = 0; j < 16; ++j) {
            float v = acc[bb][j];
#pragma unroll
            for (int m = 32; m >= 1; m >>= 1) v += __shfl_xor(v, m);
            if (lane == 0) red[wv][bb][j] = v;
        }
    __syncthreads();
    if (tid < 64) {
        int bb = tid >> 4, j = tid & 15;
        logits[bb][j] = gb[j] + red[0][bb][j] + red[1][bb][j] + red[2][bb][j] + red[3][bb][j];
    }
    __syncthreads();
    if (tid < 4) {
        int b = b0 + tid;
        float m = logits[tid][0];
#pragma unroll
        for (int j = 1; j < 16; ++j) m = fmaxf(m, logits[tid][j]);
        float ex[16], ssum = 0.f;
#pragma unroll
        for (int j = 0; j < 16; ++j) { ex[j] = __expf(logits[tid][j] - m); ssum += ex[j]; }
        float inv = 1.f / ssum;
        float o = 0.f;
#pragma unroll
        for (int j = 0; j < 16; ++j) o += ex[j] * inv * eo[(size_t)j * Bsz + b];
        out[b] = o;
    }
}

// ----------------------------------------------------------------
extern "C" void kernel_launch(void* const* d_in, const int* in_sizes, int n_in,
                              void* d_out, int out_size, void* d_ws, size_t ws_size,
                              hipStream_t stream)
{
    const float* x     = (const float*)d_in[0];
    const float* gamma = (const float*)d_in[1];
    const float* beta  = (const float*)d_in[2];
    const float* mean  = (const float*)d_in[3];
    const float* var   = (const float*)d_in[4];
    const float* k1    = (const float*)d_in[5];
    const float* r1    = (const float*)d_in[6];
    const float* b1    = (const float*)d_in[7];
    const float* k2    = (const float*)d_in[8];
    const float* r2    = (const float*)d_in[9];
    const float* b2    = (const float*)d_in[10];
    const float* dw    = (const float*)d_in[11];
    const float* db    = (const float*)d_in[12];
    const float* fc1w  = (const float*)d_in[13];
    const float* fc1b  = (const float*)d_in[14];
    const float* gw    = (const float*)d_in[15];
    const float* gb    = (const float*)d_in[16];
    float* out = (float*)d_out;

    // workspace: 33.1 MB (<= previously-proven 34.2 MB footprint)
    float* g = (float*)d_ws;                                        // 4,194,304 f (16 MB)
    unsigned short* xph = (unsigned short*)(g + (size_t)Bsz * Dd);  // 8 MB
    unsigned short* xpl = xph + (size_t)Bsz * Dd / 2 * 2;           // 8 MB
    float* pw  = (float*)(xpl + (size_t)4194304);                   // 120,320 f
    float* eo  = pw + (size_t)Ee * PWE;                             // 16,384 f

    xpack_kernel<<<2048, 256, 0, stream>>>(x, gamma, beta, mean, var, xph, xpl);
    repack2_kernel<<<(Ee * PWE + 255) / 256, 256, 0, stream>>>(k1, r1, b1, k2, r2, b2, pw);
    fused_kernel<<<512, 256, 0, stream>>>(xph, xpl, pw, dw, db, eo, x, fc1w, fc1b, g);
    gate_kernel<<<Bsz / 4, 256, 0, stream>>>(g, gw, gb, eo, out);
}

// Round 7
// 484.507 us; speedup vs baseline: 1.8328x; 1.5419x over previous
//
#include <hip/hip_runtime.h>
#include <math.h>

#define Bsz 1024
#define Tt  128
#define Ff  32
#define Ee  16
#define Hh  20
#define Dd  4096
#define EPSc 1e-3f
#define LOG2E 1.4426950408889634f

// repacked fp32 weights per expert, gate-interleaved cols c = 4*u + g (g: i,f,g,o):
// K1p[32][80]@0, R1p[20][80]@2560, K2p[20][80]@4160, R2p[20][80]@5760,
// b1p[80]@7360, b2p[80]@7440  -> 7520 floats per expert
// i/f/o gate columns (g != 2) are pre-scaled by log2(e) so sigmoid uses exp2 directly.
#define PWE 7520

typedef __attribute__((ext_vector_type(8))) short bf16x8;
typedef __attribute__((ext_vector_type(4))) float f32x4;
typedef __attribute__((ext_vector_type(4))) unsigned int u32x4;

#define MFMA16(a,b,c) __builtin_amdgcn_mfma_f32_16x16x32_bf16(a, b, c, 0, 0, 0)

__device__ __forceinline__ float sig2(float z) {      // z already scaled by log2(e)
    return __builtin_amdgcn_rcpf(1.0f + __builtin_amdgcn_exp2f(-z));
}
__device__ __forceinline__ unsigned short bf16_rne(float f) {
    unsigned u = __float_as_uint(f);
    u += 0x7FFFu + ((u >> 16) & 1u);
    return (unsigned short)(u >> 16);
}
__device__ __forceinline__ float bf16_to_f(unsigned short h) {
    return __uint_as_float(((unsigned)h) << 16);
}
// split 2 floats into packed-bf16 hi word + packed-bf16 lo word, RNE both
// (identical numerics to bf16_rne path; v_cvt_pk_bf16_f32 is RNE).
__device__ __forceinline__ void cvt2(float f0, float f1, unsigned& hp, unsigned& lp) {
    asm("v_cvt_pk_bf16_f32 %0, %1, %2" : "=v"(hp) : "v"(f0), "v"(f1));
    float h0 = __uint_as_float(hp << 16);
    float h1 = __uint_as_float(hp & 0xFFFF0000u);
    asm("v_cvt_pk_bf16_f32 %0, %1, %2" : "=v"(lp) : "v"(f0 - h0), "v"(f1 - h1));
}

// ---------------------------------------------------------------- x prepass: BN + bf16 hi/lo split
__global__ void xpack_kernel(const float* __restrict__ x,
                             const float* __restrict__ gamma, const float* __restrict__ beta,
                             const float* __restrict__ mean,  const float* __restrict__ var,
                             unsigned short* __restrict__ xph, unsigned short* __restrict__ xpl)
{
    __shared__ float sc[Ff], sh[Ff];
    int tid = threadIdx.x;
    if (tid < Ff) {
        float s = gamma[tid] * rsqrtf(var[tid] + EPSc);
        sc[tid] = s;
        sh[tid] = beta[tid] - mean[tid] * s;
    }
    __syncthreads();
    int idx = blockIdx.x * 256 + tid;           // 0 .. 64*128*64-1
    int c   = idx >> 13;
    int rem = idx & 8191;
    int t   = rem >> 6;
    int l   = rem & 63;
    int q   = l >> 4, s = l & 15;
    const float* xr = x + ((size_t)(c * 16 + s) * Tt + t) * Ff + q * 8;
    float4 v0 = *(const float4*)xr;
    float4 v1 = *(const float4*)(xr + 4);
    float xv[8] = {v0.x, v0.y, v0.z, v0.w, v1.x, v1.y, v1.z, v1.w};
    bf16x8 hv, lv;
#pragma unroll
    for (int j = 0; j < 8; ++j) {
        int f = q * 8 + j;
        float xn_ = xv[j] * sc[f] + sh[f];
        unsigned short hi = bf16_rne(xn_);
        hv[j] = (short)hi;
        lv[j] = (short)bf16_rne(xn_ - bf16_to_f(hi));
    }
    *(bf16x8*)(xph + (size_t)idx * 8) = hv;
    *(bf16x8*)(xpl + (size_t)idx * 8) = lv;
}

// ---------------------------------------------------------------- weight repack (gate-interleave)
__global__ void repack2_kernel(const float* __restrict__ k1, const float* __restrict__ r1,
                               const float* __restrict__ b1, const float* __restrict__ k2,
                               const float* __restrict__ r2, const float* __restrict__ b2,
                               float* __restrict__ pw)
{
    int idx = blockIdx.x * blockDim.x + threadIdx.x;
    if (idx >= Ee * PWE) return;
    int e = idx / PWE;
    int o = idx % PWE;
    float v;
    int g;
    if (o < 7360) {
        int c = o % 80, u = c >> 2;
        g = c & 3;
        int co = g * 20 + u;
        if (o < 2560) {
            int kk = o / 80;
            v = k1[((size_t)e * Ff + kk) * 80 + co];
        } else if (o < 4160) {
            int kk = (o - 2560) / 80;
            v = r1[((size_t)e * Hh + kk) * 80 + co];
        } else if (o < 5760) {
            int kk = (o - 4160) / 80;
            v = k2[((size_t)e * Hh + kk) * 80 + co];
        } else {
            int kk = (o - 5760) / 80;
            v = r2[((size_t)e * Hh + kk) * 80 + co];
        }
    } else if (o < 7440) {
        int c = o - 7360, u = c >> 2;
        g = c & 3;
        v = b1[(size_t)e * 80 + g * 20 + u];
    } else {
        int c = o - 7440, u = c >> 2;
        g = c & 3;
        v = b2[(size_t)e * 80 + g * 20 + u];
    }
    if (g != 2) v *= LOG2E;     // sigmoid gates -> exp2 domain
    pw[idx] = v;
}

// ---------------------------------------------------------------- fused lstm + fc1
// 512 blocks x 256 thr, 2 blocks/CU (R4-proven). Blocks i and i+256 land on the same
// CU; selector blockIdx.x<256 pairs 1 LSTM block + 1 fc1 block per CU (m114).
//
// LSTM: swapped-operand MFMA + permuted k-map; h fully register-resident (no LDS).
// fc1: 128x128 tile. A direct global->reg->cvt2 (1-step reg prefetch). W double-
// buffered LDS, one barrier per 32-K step. W prefetch = SINGLE statically-indexed
// wfp[16] with a one-iteration gap (R4-proven; R6's wfp[2] runtime ping-pong spilled
// to scratch -- rule #20 -- and cost 1.85x). W rows padded to 44 shorts (88B):
// store start-banks 22*wn mod 32 -> 4-way max; slot rotation (wn>>3)+(wn>>5) kills
// the period-32 repeat. Measured conflict count: 0 (R6).
__global__ __launch_bounds__(256, 2) void fused_kernel(
    const unsigned short* __restrict__ xph, const unsigned short* __restrict__ xpl,
    const float* __restrict__ pw, const float* __restrict__ dw, const float* __restrict__ db,
    float* __restrict__ eo,
    const float* __restrict__ x, const float* __restrict__ W,
    const float* __restrict__ bias, float* __restrict__ C)
{
    __shared__ __align__(16) char smem[45056];   // 2 x (Wsh 5632 + Wsl 5632 shorts)

    if (blockIdx.x < 256) {
        // ================= LSTM path: wave w handles tile blockIdx.x*4+w =================
        const int l = threadIdx.x & 63;
        const int q = l >> 4, s = l & 15;
        const int tile = (blockIdx.x << 2) + (threadIdx.x >> 6);
        const int e = tile >> 6;
        const int c = tile & 63;
        const int b0 = c * 16;

        const float* Wm = pw + (size_t)e * PWE;
        bf16x8 K1h[5], K1l[5], R1h[5], R1l[5], K2h[5], K2l[5], R2h[5], R2l[5];
#pragma unroll
        for (int n = 0; n < 5; ++n) {
#pragma unroll
            for (int j = 0; j < 8; ++j) {
                int k8 = q * 8 + j;         // K1: x-feature k-map (32 features)
                int uk = 4 * j + q;         // R1/K2/R2: permuted h-unit k-map (j<5 valid)
                int cc = n * 16 + s;
                float wv_;
                unsigned short hi; float hf;
                wv_ = Wm[k8 * 80 + cc];
                hi = bf16_rne(wv_); hf = bf16_to_f(hi);
                K1h[n][j] = (short)hi; K1l[n][j] = (short)bf16_rne(wv_ - hf);
                wv_ = (j < 5) ? Wm[2560 + uk * 80 + cc] : 0.f;
                hi = bf16_rne(wv_); hf = bf16_to_f(hi);
                R1h[n][j] = (short)hi; R1l[n][j] = (short)bf16_rne(wv_ - hf);
                wv_ = (j < 5) ? Wm[4160 + uk * 80 + cc] : 0.f;
                hi = bf16_rne(wv_); hf = bf16_to_f(hi);
                K2h[n][j] = (short)hi; K2l[n][j] = (short)bf16_rne(wv_ - hf);
                wv_ = (j < 5) ? Wm[5760 + uk * 80 + cc] : 0.f;
                hi = bf16_rne(wv_); hf = bf16_to_f(hi);
                R2h[n][j] = (short)hi; R2l[n][j] = (short)bf16_rne(wv_ - hf);
            }
        }
        f32x4 bf1[5], bf2[5];
        float dwr[5];
#pragma unroll
        for (int n = 0; n < 5; ++n) {
            bf1[n] = *(const f32x4*)&Wm[7360 + n * 16 + 4 * q];
            bf2[n] = *(const f32x4*)&Wm[7440 + n * 16 + 4 * q];
            dwr[n] = dw[e * Hh + 4 * n + q];
        }

        float c1[5] = {0, 0, 0, 0, 0}, c2[5] = {0, 0, 0, 0, 0};
        float h2reg[5] = {0, 0, 0, 0, 0};

        const bf16x8 z8 = {0, 0, 0, 0, 0, 0, 0, 0};
        bf16x8 H1a = z8, H1b = z8, H2a = z8, H2b = z8;   // h[t-1] fragments, reg-resident

        const unsigned short* xbh = xph + (size_t)c * 65536 + l * 8;
        const unsigned short* xbl = xpl + (size_t)c * 65536 + l * 8;
        bf16x8 xch = *(const bf16x8*)xbh;
        bf16x8 xcl = *(const bf16x8*)xbl;

#pragma unroll 1
        for (int t = 0; t < Tt; ++t) {
            bf16x8 xnh = xch, xnl = xcl;
            if (t < Tt - 1) {       // prefetch t+1 (overlaps this step's compute)
                xnh = *(const bf16x8*)(xbh + (t + 1) * 512);
                xnl = *(const bf16x8*)(xbl + (t + 1) * 512);
            }

            // ---- layer 1: z^T = K1^T x^T + R1^T h1^T  (x first, fresh H1 last)
            f32x4 a1[5];
#pragma unroll
            for (int n = 0; n < 5; ++n) {
                f32x4 acc = bf1[n];
                acc = MFMA16(K1h[n], xch, acc);
                acc = MFMA16(K1l[n], xch, acc);
                acc = MFMA16(K1h[n], xcl, acc);
                acc = MFMA16(R1h[n], H1a, acc);
                acc = MFMA16(R1l[n], H1a, acc);
                acc = MFMA16(R1h[n], H1b, acc);
                a1[n] = acc;
            }
            {
                float hv[5];
#pragma unroll
                for (int n = 0; n < 5; ++n) {
                    float iv = sig2(a1[n][0]);
                    float fv = sig2(a1[n][1]);
                    float gv = fmaxf(a1[n][2], 0.f);
                    float ov = sig2(a1[n][3]);
                    c1[n] = fv * c1[n] + iv * gv;
                    hv[n] = ov * fmaxf(c1[n], 0.f);
                }
                unsigned h0, h1, h2, l0, l1, l2;
                cvt2(hv[0], hv[1], h0, l0);
                cvt2(hv[2], hv[3], h1, l1);
                cvt2(hv[4], 0.f,   h2, l2);
                u32x4 uh = {h0, h1, h2, 0u}, ul = {l0, l1, l2, 0u};
                H1a = __builtin_bit_cast(bf16x8, uh);
                H1b = __builtin_bit_cast(bf16x8, ul);
            }

            // ---- layer 2: stale H2 first, freshly-packed H1 last (cvt2 slack)
            f32x4 a2[5];
#pragma unroll
            for (int n = 0; n < 5; ++n) {
                f32x4 acc = bf2[n];
                acc = MFMA16(R2h[n], H2a, acc);
                acc = MFMA16(R2l[n], H2a, acc);
                acc = MFMA16(R2h[n], H2b, acc);
                acc = MFMA16(K2h[n], H1a, acc);
                acc = MFMA16(K2l[n], H1a, acc);
                acc = MFMA16(K2h[n], H1b, acc);
                a2[n] = acc;
            }
            {
                float hv[5];
#pragma unroll
                for (int n = 0; n < 5; ++n) {
                    float iv = sig2(a2[n][0]);
                    float fv = sig2(a2[n][1]);
                    float gv = fmaxf(a2[n][2], 0.f);
                    float ov = sig2(a2[n][3]);
                    c2[n] = fv * c2[n] + iv * gv;
                    float h = ov * fmaxf(c2[n], 0.f);
                    h2reg[n] = h;
                    hv[n] = h;
                }
                unsigned h0, h1, h2, l0, l1, l2;
                cvt2(hv[0], hv[1], h0, l0);
                cvt2(hv[2], hv[3], h1, l1);
                cvt2(hv[4], 0.f,   h2, l2);
                u32x4 uh = {h0, h1, h2, 0u}, ul = {l0, l1, l2, 0u};
                H2a = __builtin_bit_cast(bf16x8, uh);
                H2b = __builtin_bit_cast(bf16x8, ul);
            }

            xch = xnh; xcl = xnl;
        }

        float p = 0.f;
#pragma unroll
        for (int n = 0; n < 5; ++n) p += h2reg[n] * dwr[n];
        p += __shfl_xor(p, 16);
        p += __shfl_xor(p, 32);
        if (q == 0) eo[(size_t)e * Bsz + b0 + s] = db[e] + p;

    } else {
        // ================= fc1 path: 128x128, A-direct + W-dbuf =================
        const int tid = threadIdx.x;
        const int wv = tid >> 6, l = tid & 63, q = l >> 4, s = l & 15;
        const int id = blockIdx.x & 255;
        const int n0 = (id & 31) * 128, m0 = (id >> 5) * 128;
        const int wr = (wv & 1) * 64, wc = (wv >> 1) * 64;

        const int wn = tid & 127, wkq = tid >> 7;
        // physical slot for W stores: logical slots {2*wkq, 2*wkq+1}
        const int wrot = ((wn >> 3) + (wn >> 5)) & 3;
        const int ws0 = ((wkq * 2) + wrot) & 3;
        const int ws1 = ((wkq * 2 + 1) + wrot) & 3;

        const float* WG = W + (size_t)(wkq * 16) * Dd + n0 + wn;
        const float* Arow = x + (size_t)(m0 + wr + s) * Dd + q * 8;

        unsigned short* lds = (unsigned short*)smem;   // [2][ Wsh 5632 | Wsl 5632 ] (44/row)

        f32x4 acc[4][4];
#pragma unroll
        for (int mt = 0; mt < 4; ++mt)
#pragma unroll
            for (int nt = 0; nt < 4; ++nt) acc[mt][nt] = (f32x4){0.f, 0.f, 0.f, 0.f};

        float wfp[16];          // single statically-indexed prefetch buffer (rule #20)
        float4 afc[8];

        {   // prologue: W step0 -> buf0; W step1 -> wfp; A step0 -> afc
            float w0[16];
#pragma unroll
            for (int i = 0; i < 16; ++i) w0[i] = WG[(size_t)i * Dd];
            uint4 h0, l0, h1, l1;
            cvt2(w0[0],  w0[1],  h0.x, l0.x); cvt2(w0[2],  w0[3],  h0.y, l0.y);
            cvt2(w0[4],  w0[5],  h0.z, l0.z); cvt2(w0[6],  w0[7],  h0.w, l0.w);
            cvt2(w0[8],  w0[9],  h1.x, l1.x); cvt2(w0[10], w0[11], h1.y, l1.y);
            cvt2(w0[12], w0[13], h1.z, l1.z); cvt2(w0[14], w0[15], h1.w, l1.w);
            *(uint4*)&lds[wn * 44 + ws0 * 8]          = h0;
            *(uint4*)&lds[5632 + wn * 44 + ws0 * 8]   = l0;
            *(uint4*)&lds[wn * 44 + ws1 * 8]          = h1;
            *(uint4*)&lds[5632 + wn * 44 + ws1 * 8]   = l1;
#pragma unroll
            for (int i = 0; i < 16; ++i) wfp[i] = WG[(size_t)(32 + i) * Dd];
#pragma unroll
            for (int mt = 0; mt < 4; ++mt) {
                afc[mt * 2]     = *(const float4*)(Arow + (size_t)mt * 16 * Dd);
                afc[mt * 2 + 1] = *(const float4*)(Arow + (size_t)mt * 16 * Dd + 4);
            }
            __syncthreads();
        }

#pragma unroll 1
        for (int it = 0; it < 128; ++it) {
            const int k0 = it * 32;
            unsigned short* cb = lds + (it & 1) * 11264;        // compute buffer (step it)
            unsigned short* sb = lds + ((it & 1) ^ 1) * 11264;  // store buffer (step it+1)

            // phase 1: store W(step it+1) from wfp (loaded last iteration)
            if (it < 127) {
                uint4 h0, l0, h1, l1;
                cvt2(wfp[0],  wfp[1],  h0.x, l0.x); cvt2(wfp[2],  wfp[3],  h0.y, l0.y);
                cvt2(wfp[4],  wfp[5],  h0.z, l0.z); cvt2(wfp[6],  wfp[7],  h0.w, l0.w);
                cvt2(wfp[8],  wfp[9],  h1.x, l1.x); cvt2(wfp[10], wfp[11], h1.y, l1.y);
                cvt2(wfp[12], wfp[13], h1.z, l1.z); cvt2(wfp[14], wfp[15], h1.w, l1.w);
                *(uint4*)&sb[wn * 44 + ws0 * 8]        = h0;
                *(uint4*)&sb[5632 + wn * 44 + ws0 * 8] = l0;
                *(uint4*)&sb[wn * 44 + ws1 * 8]        = h1;
                *(uint4*)&sb[5632 + wn * 44 + ws1 * 8] = l1;
            }

            // phase 2: issue W global loads for step it+2
            {
                const int kW = (it + 2 < 128) ? k0 + 64 : k0;
#pragma unroll
                for (int i = 0; i < 16; ++i) wfp[i] = WG[(size_t)(kW + i) * Dd];
            }

            // phase 3: W fragments from compute buffer (slot-swizzled)
            bf16x8 Wfh[4], Wfl[4];
#pragma unroll
            for (int nt = 0; nt < 4; ++nt) {
                const int row = wc + nt * 16 + s;
                const int ps = (q + ((row >> 3) + (row >> 5))) & 3;
                Wfh[nt] = *(bf16x8*)&cb[row * 44 + ps * 8];
                Wfl[nt] = *(bf16x8*)&cb[5632 + row * 44 + ps * 8];
            }

            // phase 4: A fragments from prefetched regs; issue A loads for it+1
            bf16x8 Afh[4], Afl[4];
#pragma unroll
            for (int mt = 0; mt < 4; ++mt) {
                uint4 uh, ul;
                cvt2(afc[mt * 2].x,     afc[mt * 2].y,     uh.x, ul.x);
                cvt2(afc[mt * 2].z,     afc[mt * 2].w,     uh.y, ul.y);
                cvt2(afc[mt * 2 + 1].x, afc[mt * 2 + 1].y, uh.z, ul.z);
                cvt2(afc[mt * 2 + 1].z, afc[mt * 2 + 1].w, uh.w, ul.w);
                Afh[mt] = __builtin_bit_cast(bf16x8, uh);
                Afl[mt] = __builtin_bit_cast(bf16x8, ul);
            }
            {
                const int kA = (it + 1 < 128) ? k0 + 32 : k0;
#pragma unroll
                for (int mt = 0; mt < 4; ++mt) {
                    afc[mt * 2]     = *(const float4*)(Arow + (size_t)mt * 16 * Dd + kA);
                    afc[mt * 2 + 1] = *(const float4*)(Arow + (size_t)mt * 16 * Dd + kA + 4);
                }
            }

            // phase 5: MFMA
#pragma unroll
            for (int mt = 0; mt < 4; ++mt)
#pragma unroll
                for (int nt = 0; nt < 4; ++nt) {
                    f32x4 a = acc[mt][nt];
                    a = MFMA16(Afl[mt], Wfh[nt], a);
                    a = MFMA16(Afh[mt], Wfl[nt], a);
                    a = MFMA16(Afh[mt], Wfh[nt], a);
                    acc[mt][nt] = a;
                }

            // phase 6: one barrier per step
            __syncthreads();
        }

#pragma unroll
        for (int nt = 0; nt < 4; ++nt) {
            float bv = bias[n0 + wc + nt * 16 + s];
#pragma unroll
            for (int mt = 0; mt < 4; ++mt)
#pragma unroll
                for (int r = 0; r < 4; ++r) {
                    int m = m0 + wr + mt * 16 + q * 4 + r;
                    C[(size_t)m * Dd + n0 + wc + nt * 16 + s] = fmaxf(acc[mt][nt][r] + bv, 0.f);
                }
        }
    }
}

// ---------------------------------------------------------------- gate: softmax(g @ gate_w + gb) + combine
// 4 batch rows per block (256 blocks): gate_w vectors loaded once, reused x4
// -> gate_w L2/L3 traffic 256MB -> 64MB.
__global__ __launch_bounds__(256) void gate_kernel(const float* __restrict__ g,
                                                   const float* __restrict__ gw,
                                                   const float* __restrict__ gb,
                                                   const float* __restrict__ eo,
                                                   float* __restrict__ out)
{
    int b0 = blockIdx.x * 4;
    int tid = threadIdx.x;
    int lane = tid & 63;
    int wv = tid >> 6;

    float acc[4][16];
#pragma unroll
    for (int bb = 0; bb < 4; ++bb)
#pragma unroll
        for (int j = 0; j < 16; ++j) acc[bb][j] = 0.f;

    const float* g0 = g + (size_t)b0 * Dd;
#pragma unroll
    for (int it = 0; it < Dd / 256; ++it) {
        int d = tid + it * 256;
        const float4* wr_ = (const float4*)(gw + (size_t)d * 16);
        float4 w0 = wr_[0], w1 = wr_[1], w2 = wr_[2], w3 = wr_[3];
        float gv[4];
#pragma unroll
        for (int bb = 0; bb < 4; ++bb) gv[bb] = g0[(size_t)bb * Dd + d];
#pragma unroll
        for (int bb = 0; bb < 4; ++bb) {
            float v = gv[bb];
            acc[bb][0]  += v * w0.x;  acc[bb][1]  += v * w0.y;
            acc[bb][2]  += v * w0.z;  acc[bb][3]  += v * w0.w;
            acc[bb][4]  += v * w1.x;  acc[bb][5]  += v * w1.y;
            acc[bb][6]  += v * w1.z;  acc[bb][7]  += v * w1.w;
            acc[bb][8]  += v * w2.x;  acc[bb][9]  += v * w2.y;
            acc[bb][10] += v * w2.z;  acc[bb][11] += v * w2.w;
            acc[bb][12] += v * w3.x;  acc[bb][13] += v * w3.y;
            acc[bb][14] += v * w3.z;  acc[bb][15] += v * w3.w;
        }
    }

    __shared__ float red[4][4][16];     // [wave][bb][j]
    __shared__ float logits[4][16];
#pragma unroll
    for (int bb = 0; bb < 4; ++bb)
#pragma unroll
        for (int j = 0; j < 16; ++j) {
            float v = acc[bb][j];
#pragma unroll
            for (int m = 32; m >= 1; m >>= 1) v += __shfl_xor(v, m);
            if (lane == 0) red[wv][bb][j] = v;
        }
    __syncthreads();
    if (tid < 64) {
        int bb = tid >> 4, j = tid & 15;
        logits[bb][j] = gb[j] + red[0][bb][j] + red[1][bb][j] + red[2][bb][j] + red[3][bb][j];
    }
    __syncthreads();
    if (tid < 4) {
        int b = b0 + tid;
        float m = logits[tid][0];
#pragma unroll
        for (int j = 1; j < 16; ++j) m = fmaxf(m, logits[tid][j]);
        float ex[16], ssum = 0.f;
#pragma unroll
        for (int j = 0; j < 16; ++j) { ex[j] = __expf(logits[tid][j] - m); ssum += ex[j]; }
        float inv = 1.f / ssum;
        float o = 0.f;
#pragma unroll
        for (int j = 0; j < 16; ++j) o += ex[j] * inv * eo[(size_t)j * Bsz + b];
        out[b] = o;
    }
}

// ----------------------------------------------------------------
extern "C" void kernel_launch(void* const* d_in, const int* in_sizes, int n_in,
                              void* d_out, int out_size, void* d_ws, size_t ws_size,
                              hipStream_t stream)
{
    const float* x     = (const float*)d_in[0];
    const float* gamma = (const float*)d_in[1];
    const float* beta  = (const float*)d_in[2];
    const float* mean  = (const float*)d_in[3];
    const float* var   = (const float*)d_in[4];
    const float* k1    = (const float*)d_in[5];
    const float* r1    = (const float*)d_in[6];
    const float* b1    = (const float*)d_in[7];
    const float* k2    = (const float*)d_in[8];
    const float* r2    = (const float*)d_in[9];
    const float* b2    = (const float*)d_in[10];
    const float* dw    = (const float*)d_in[11];
    const float* db    = (const float*)d_in[12];
    const float* fc1w  = (const float*)d_in[13];
    const float* fc1b  = (const float*)d_in[14];
    const float* gw    = (const float*)d_in[15];
    const float* gb    = (const float*)d_in[16];
    float* out = (float*)d_out;

    // workspace: 33.1 MB (<= previously-proven 34.2 MB footprint)
    float* g = (float*)d_ws;                                        // 4,194,304 f (16 MB)
    unsigned short* xph = (unsigned short*)(g + (size_t)Bsz * Dd);  // 8 MB
    unsigned short* xpl = xph + (size_t)Bsz * Dd / 2 * 2;           // 8 MB
    float* pw  = (float*)(xpl + (size_t)4194304);                   // 120,320 f
    float* eo  = pw + (size_t)Ee * PWE;                             // 16,384 f

    xpack_kernel<<<2048, 256, 0, stream>>>(x, gamma, beta, mean, var, xph, xpl);
    repack2_kernel<<<(Ee * PWE + 255) / 256, 256, 0, stream>>>(k1, r1, b1, k2, r2, b2, pw);
    fused_kernel<<<512, 256, 0, stream>>>(xph, xpl, pw, dw, db, eo, x, fc1w, fc1b, g);
    gate_kernel<<<Bsz / 4, 256, 0, stream>>>(g, gw, gb, eo, out);
}

// Round 8
// 450.003 us; speedup vs baseline: 1.9733x; 1.0767x over previous
//
#include <hip/hip_runtime.h>
#include <math.h>

#define Bsz 1024
#define Tt  128
#define Ff  32
#define Ee  16
#define Hh  20
#define Dd  4096
#define EPSc 1e-3f
#define LOG2E 1.4426950408889634f

// repacked fp32 weights per expert, gate-interleaved cols c = 4*u + g (g: i,f,g,o):
// K1p[32][80]@0, R1p[20][80]@2560, K2p[20][80]@4160, R2p[20][80]@5760,
// b1p[80]@7360, b2p[80]@7440  -> 7520 floats per expert
// i/f/o gate columns (g != 2) are pre-scaled by log2(e) so sigmoid uses exp2 directly.
#define PWE 7520

typedef __attribute__((ext_vector_type(8))) short bf16x8;
typedef __attribute__((ext_vector_type(4))) float f32x4;
typedef __attribute__((ext_vector_type(4))) unsigned int u32x4;

#define MFMA16(a,b,c) __builtin_amdgcn_mfma_f32_16x16x32_bf16(a, b, c, 0, 0, 0)

__device__ __forceinline__ float sig2(float z) {      // z already scaled by log2(e)
    return __builtin_amdgcn_rcpf(1.0f + __builtin_amdgcn_exp2f(-z));
}
__device__ __forceinline__ unsigned short bf16_rne(float f) {
    unsigned u = __float_as_uint(f);
    u += 0x7FFFu + ((u >> 16) & 1u);
    return (unsigned short)(u >> 16);
}
__device__ __forceinline__ float bf16_to_f(unsigned short h) {
    return __uint_as_float(((unsigned)h) << 16);
}
// split 2 floats into packed-bf16 hi word + packed-bf16 lo word, RNE both
// (identical numerics to bf16_rne path; v_cvt_pk_bf16_f32 is RNE).
__device__ __forceinline__ void cvt2(float f0, float f1, unsigned& hp, unsigned& lp) {
    asm("v_cvt_pk_bf16_f32 %0, %1, %2" : "=v"(hp) : "v"(f0), "v"(f1));
    float h0 = __uint_as_float(hp << 16);
    float h1 = __uint_as_float(hp & 0xFFFF0000u);
    asm("v_cvt_pk_bf16_f32 %0, %1, %2" : "=v"(lp) : "v"(f0 - h0), "v"(f1 - h1));
}

// ---------------------------------------------------------------- x prepass: BN + bf16 hi/lo split
__global__ void xpack_kernel(const float* __restrict__ x,
                             const float* __restrict__ gamma, const float* __restrict__ beta,
                             const float* __restrict__ mean,  const float* __restrict__ var,
                             unsigned short* __restrict__ xph, unsigned short* __restrict__ xpl)
{
    __shared__ float sc[Ff], sh[Ff];
    int tid = threadIdx.x;
    if (tid < Ff) {
        float s = gamma[tid] * rsqrtf(var[tid] + EPSc);
        sc[tid] = s;
        sh[tid] = beta[tid] - mean[tid] * s;
    }
    __syncthreads();
    int idx = blockIdx.x * 256 + tid;           // 0 .. 64*128*64-1
    int c   = idx >> 13;
    int rem = idx & 8191;
    int t   = rem >> 6;
    int l   = rem & 63;
    int q   = l >> 4, s = l & 15;
    const float* xr = x + ((size_t)(c * 16 + s) * Tt + t) * Ff + q * 8;
    float4 v0 = *(const float4*)xr;
    float4 v1 = *(const float4*)(xr + 4);
    float xv[8] = {v0.x, v0.y, v0.z, v0.w, v1.x, v1.y, v1.z, v1.w};
    bf16x8 hv, lv;
#pragma unroll
    for (int j = 0; j < 8; ++j) {
        int f = q * 8 + j;
        float xn_ = xv[j] * sc[f] + sh[f];
        unsigned short hi = bf16_rne(xn_);
        hv[j] = (short)hi;
        lv[j] = (short)bf16_rne(xn_ - bf16_to_f(hi));
    }
    *(bf16x8*)(xph + (size_t)idx * 8) = hv;
    *(bf16x8*)(xpl + (size_t)idx * 8) = lv;
}

// ---------------------------------------------------------------- weight repack (gate-interleave)
__global__ void repack2_kernel(const float* __restrict__ k1, const float* __restrict__ r1,
                               const float* __restrict__ b1, const float* __restrict__ k2,
                               const float* __restrict__ r2, const float* __restrict__ b2,
                               float* __restrict__ pw)
{
    int idx = blockIdx.x * blockDim.x + threadIdx.x;
    if (idx >= Ee * PWE) return;
    int e = idx / PWE;
    int o = idx % PWE;
    float v;
    int g;
    if (o < 7360) {
        int c = o % 80, u = c >> 2;
        g = c & 3;
        int co = g * 20 + u;
        if (o < 2560) {
            int kk = o / 80;
            v = k1[((size_t)e * Ff + kk) * 80 + co];
        } else if (o < 4160) {
            int kk = (o - 2560) / 80;
            v = r1[((size_t)e * Hh + kk) * 80 + co];
        } else if (o < 5760) {
            int kk = (o - 4160) / 80;
            v = k2[((size_t)e * Hh + kk) * 80 + co];
        } else {
            int kk = (o - 5760) / 80;
            v = r2[((size_t)e * Hh + kk) * 80 + co];
        }
    } else if (o < 7440) {
        int c = o - 7360, u = c >> 2;
        g = c & 3;
        v = b1[(size_t)e * 80 + g * 20 + u];
    } else {
        int c = o - 7440, u = c >> 2;
        g = c & 3;
        v = b2[(size_t)e * 80 + g * 20 + u];
    }
    if (g != 2) v *= LOG2E;     // sigmoid gates -> exp2 domain
    pw[idx] = v;
}

// ---------------------------------------------------------------- fused lstm + fc1
// 512 blocks x 256 thr, 2 blocks/CU. Blocks i and i+256 land on the same CU; selector
// blockIdx.x<256 pairs 1 LSTM block + 1 fc1 block per CU (m114 co-scheduling).
//
// LSTM: swapped-operand MFMA + permuted k-map; h fully register-resident (no LDS).
// fc1: 128x128 tile. A direct global->reg->cvt2 (1-step reg prefetch). W double-
// buffered LDS, one barrier per 32-K step, single statically-indexed wfp[16]
// prefetch (rule #20). W LDS layout: ONE combined row per n-col = 64 shorts (128B),
// 8 slots of 16B (lslot 0-3 = hi k-chunks, 4-7 = lo k-chunks), XOR-swizzled:
// phys = lslot ^ (row & 7). All addresses 128*row + 16*phys -> 16B-ALIGNED always
// (R3's stride-42 and R7's stride-44 "odd stride" fixes broke b128 alignment on
// odd rows -- bank spreading must come from slot permutation, not row stride).
// Writes: bank-start 4*(wn&7), uniform 8 accesses/bank = structural min.
// Reads: phys = q^(s&7), uniform 8/bank. Both conflict-free. LDS: 32KB/block.
__global__ __launch_bounds__(256, 2) void fused_kernel(
    const unsigned short* __restrict__ xph, const unsigned short* __restrict__ xpl,
    const float* __restrict__ pw, const float* __restrict__ dw, const float* __restrict__ db,
    float* __restrict__ eo,
    const float* __restrict__ x, const float* __restrict__ W,
    const float* __restrict__ bias, float* __restrict__ C)
{
    __shared__ __align__(16) char smem[32768];   // 2 x (128 rows x 64 shorts)

    if (blockIdx.x < 256) {
        // ================= LSTM path: wave w handles tile blockIdx.x*4+w =================
        const int l = threadIdx.x & 63;
        const int q = l >> 4, s = l & 15;
        const int tile = (blockIdx.x << 2) + (threadIdx.x >> 6);
        const int e = tile >> 6;
        const int c = tile & 63;
        const int b0 = c * 16;

        const float* Wm = pw + (size_t)e * PWE;
        bf16x8 K1h[5], K1l[5], R1h[5], R1l[5], K2h[5], K2l[5], R2h[5], R2l[5];
#pragma unroll
        for (int n = 0; n < 5; ++n) {
#pragma unroll
            for (int j = 0; j < 8; ++j) {
                int k8 = q * 8 + j;         // K1: x-feature k-map (32 features)
                int uk = 4 * j + q;         // R1/K2/R2: permuted h-unit k-map (j<5 valid)
                int cc = n * 16 + s;
                float wv_;
                unsigned short hi; float hf;
                wv_ = Wm[k8 * 80 + cc];
                hi = bf16_rne(wv_); hf = bf16_to_f(hi);
                K1h[n][j] = (short)hi; K1l[n][j] = (short)bf16_rne(wv_ - hf);
                wv_ = (j < 5) ? Wm[2560 + uk * 80 + cc] : 0.f;
                hi = bf16_rne(wv_); hf = bf16_to_f(hi);
                R1h[n][j] = (short)hi; R1l[n][j] = (short)bf16_rne(wv_ - hf);
                wv_ = (j < 5) ? Wm[4160 + uk * 80 + cc] : 0.f;
                hi = bf16_rne(wv_); hf = bf16_to_f(hi);
                K2h[n][j] = (short)hi; K2l[n][j] = (short)bf16_rne(wv_ - hf);
                wv_ = (j < 5) ? Wm[5760 + uk * 80 + cc] : 0.f;
                hi = bf16_rne(wv_); hf = bf16_to_f(hi);
                R2h[n][j] = (short)hi; R2l[n][j] = (short)bf16_rne(wv_ - hf);
            }
        }
        f32x4 bf1[5], bf2[5];
        float dwr[5];
#pragma unroll
        for (int n = 0; n < 5; ++n) {
            bf1[n] = *(const f32x4*)&Wm[7360 + n * 16 + 4 * q];
            bf2[n] = *(const f32x4*)&Wm[7440 + n * 16 + 4 * q];
            dwr[n] = dw[e * Hh + 4 * n + q];
        }

        float c1[5] = {0, 0, 0, 0, 0}, c2[5] = {0, 0, 0, 0, 0};
        float h2reg[5] = {0, 0, 0, 0, 0};

        const bf16x8 z8 = {0, 0, 0, 0, 0, 0, 0, 0};
        bf16x8 H1a = z8, H1b = z8, H2a = z8, H2b = z8;   // h[t-1] fragments, reg-resident

        const unsigned short* xbh = xph + (size_t)c * 65536 + l * 8;
        const unsigned short* xbl = xpl + (size_t)c * 65536 + l * 8;
        bf16x8 xch = *(const bf16x8*)xbh;
        bf16x8 xcl = *(const bf16x8*)xbl;

#pragma unroll 1
        for (int t = 0; t < Tt; ++t) {
            bf16x8 xnh = xch, xnl = xcl;
            if (t < Tt - 1) {       // prefetch t+1 (overlaps this step's compute)
                xnh = *(const bf16x8*)(xbh + (t + 1) * 512);
                xnl = *(const bf16x8*)(xbl + (t + 1) * 512);
            }

            // ---- layer 1: z^T = K1^T x^T + R1^T h1^T  (x first, fresh H1 last)
            f32x4 a1[5];
#pragma unroll
            for (int n = 0; n < 5; ++n) {
                f32x4 acc = bf1[n];
                acc = MFMA16(K1h[n], xch, acc);
                acc = MFMA16(K1l[n], xch, acc);
                acc = MFMA16(K1h[n], xcl, acc);
                acc = MFMA16(R1h[n], H1a, acc);
                acc = MFMA16(R1l[n], H1a, acc);
                acc = MFMA16(R1h[n], H1b, acc);
                a1[n] = acc;
            }
            {
                float hv[5];
#pragma unroll
                for (int n = 0; n < 5; ++n) {
                    float iv = sig2(a1[n][0]);
                    float fv = sig2(a1[n][1]);
                    float gv = fmaxf(a1[n][2], 0.f);
                    float ov = sig2(a1[n][3]);
                    c1[n] = fv * c1[n] + iv * gv;
                    hv[n] = ov * fmaxf(c1[n], 0.f);
                }
                unsigned h0, h1, h2, l0, l1, l2;
                cvt2(hv[0], hv[1], h0, l0);
                cvt2(hv[2], hv[3], h1, l1);
                cvt2(hv[4], 0.f,   h2, l2);
                u32x4 uh = {h0, h1, h2, 0u}, ul = {l0, l1, l2, 0u};
                H1a = __builtin_bit_cast(bf16x8, uh);
                H1b = __builtin_bit_cast(bf16x8, ul);
            }

            // ---- layer 2: stale H2 first, freshly-packed H1 last (cvt2 slack)
            f32x4 a2[5];
#pragma unroll
            for (int n = 0; n < 5; ++n) {
                f32x4 acc = bf2[n];
                acc = MFMA16(R2h[n], H2a, acc);
                acc = MFMA16(R2l[n], H2a, acc);
                acc = MFMA16(R2h[n], H2b, acc);
                acc = MFMA16(K2h[n], H1a, acc);
                acc = MFMA16(K2l[n], H1a, acc);
                acc = MFMA16(K2h[n], H1b, acc);
                a2[n] = acc;
            }
            {
                float hv[5];
#pragma unroll
                for (int n = 0; n < 5; ++n) {
                    float iv = sig2(a2[n][0]);
                    float fv = sig2(a2[n][1]);
                    float gv = fmaxf(a2[n][2], 0.f);
                    float ov = sig2(a2[n][3]);
                    c2[n] = fv * c2[n] + iv * gv;
                    float h = ov * fmaxf(c2[n], 0.f);
                    h2reg[n] = h;
                    hv[n] = h;
                }
                unsigned h0, h1, h2, l0, l1, l2;
                cvt2(hv[0], hv[1], h0, l0);
                cvt2(hv[2], hv[3], h1, l1);
                cvt2(hv[4], 0.f,   h2, l2);
                u32x4 uh = {h0, h1, h2, 0u}, ul = {l0, l1, l2, 0u};
                H2a = __builtin_bit_cast(bf16x8, uh);
                H2b = __builtin_bit_cast(bf16x8, ul);
            }

            xch = xnh; xcl = xnl;
        }

        float p = 0.f;
#pragma unroll
        for (int n = 0; n < 5; ++n) p += h2reg[n] * dwr[n];
        p += __shfl_xor(p, 16);
        p += __shfl_xor(p, 32);
        if (q == 0) eo[(size_t)e * Bsz + b0 + s] = db[e] + p;

    } else {
        // ================= fc1 path: 128x128, A-direct + W-dbuf =================
        const int tid = threadIdx.x;
        const int wv = tid >> 6, l = tid & 63, q = l >> 4, s = l & 15;
        const int id = blockIdx.x & 255;
        const int n0 = (id & 31) * 128, m0 = (id >> 5) * 128;
        const int wr = (wv & 1) * 64, wc = (wv >> 1) * 64;

        const int wn = tid & 127, wkq = tid >> 7;
        const int r7w = wn & 7;                       // XOR swizzle key for writes
        // physical slots for this thread's 4 stores (lslots 2wkq,2wkq+1,4+2wkq,5+2wkq)
        const int pw0 = ((2 * wkq)     ^ r7w) * 8;
        const int pw1 = ((2 * wkq + 1) ^ r7w) * 8;
        const int pw2 = ((4 + 2 * wkq) ^ r7w) * 8;
        const int pw3 = ((5 + 2 * wkq) ^ r7w) * 8;

        const float* WG = W + (size_t)(wkq * 16) * Dd + n0 + wn;
        const float* Arow = x + (size_t)(m0 + wr + s) * Dd + q * 8;

        unsigned short* lds = (unsigned short*)smem;   // [2][128 rows][64 shorts]

        f32x4 acc[4][4];
#pragma unroll
        for (int mt = 0; mt < 4; ++mt)
#pragma unroll
            for (int nt = 0; nt < 4; ++nt) acc[mt][nt] = (f32x4){0.f, 0.f, 0.f, 0.f};

        float wfp[16];          // single statically-indexed prefetch buffer (rule #20)
        float4 afc[8];

        {   // prologue: W step0 -> buf0; W step1 -> wfp; A step0 -> afc
            float w0[16];
#pragma unroll
            for (int i = 0; i < 16; ++i) w0[i] = WG[(size_t)i * Dd];
            uint4 h0, l0, h1, l1;
            cvt2(w0[0],  w0[1],  h0.x, l0.x); cvt2(w0[2],  w0[3],  h0.y, l0.y);
            cvt2(w0[4],  w0[5],  h0.z, l0.z); cvt2(w0[6],  w0[7],  h0.w, l0.w);
            cvt2(w0[8],  w0[9],  h1.x, l1.x); cvt2(w0[10], w0[11], h1.y, l1.y);
            cvt2(w0[12], w0[13], h1.z, l1.z); cvt2(w0[14], w0[15], h1.w, l1.w);
            unsigned short* rb = lds + wn * 64;
            *(uint4*)&rb[pw0] = h0;
            *(uint4*)&rb[pw1] = h1;
            *(uint4*)&rb[pw2] = l0;
            *(uint4*)&rb[pw3] = l1;
#pragma unroll
            for (int i = 0; i < 16; ++i) wfp[i] = WG[(size_t)(32 + i) * Dd];
#pragma unroll
            for (int mt = 0; mt < 4; ++mt) {
                afc[mt * 2]     = *(const float4*)(Arow + (size_t)mt * 16 * Dd);
                afc[mt * 2 + 1] = *(const float4*)(Arow + (size_t)mt * 16 * Dd + 4);
            }
            __syncthreads();
        }

#pragma unroll 1
        for (int it = 0; it < 128; ++it) {
            const int k0 = it * 32;
            unsigned short* cb = lds + (it & 1) * 8192;        // compute buffer (step it)
            unsigned short* sb = lds + ((it & 1) ^ 1) * 8192;  // store buffer (step it+1)

            // phase 1: store W(step it+1) from wfp (loaded last iteration)
            if (it < 127) {
                uint4 h0, l0, h1, l1;
                cvt2(wfp[0],  wfp[1],  h0.x, l0.x); cvt2(wfp[2],  wfp[3],  h0.y, l0.y);
                cvt2(wfp[4],  wfp[5],  h0.z, l0.z); cvt2(wfp[6],  wfp[7],  h0.w, l0.w);
                cvt2(wfp[8],  wfp[9],  h1.x, l1.x); cvt2(wfp[10], wfp[11], h1.y, l1.y);
                cvt2(wfp[12], wfp[13], h1.z, l1.z); cvt2(wfp[14], wfp[15], h1.w, l1.w);
                unsigned short* rb = sb + wn * 64;
                *(uint4*)&rb[pw0] = h0;
                *(uint4*)&rb[pw1] = h1;
                *(uint4*)&rb[pw2] = l0;
                *(uint4*)&rb[pw3] = l1;
            }

            // phase 2: issue W global loads for step it+2
            {
                const int kW = (it + 2 < 128) ? k0 + 64 : k0;
#pragma unroll
                for (int i = 0; i < 16; ++i) wfp[i] = WG[(size_t)(kW + i) * Dd];
            }

            // phase 3: W fragments from compute buffer (XOR slot swizzle)
            bf16x8 Wfh[4], Wfl[4];
            {
                const int r7r = s & 7;                 // row&7 = s&7 (wc, nt*16 mult of 16)
                const int ph = (q ^ r7r) * 8;
                const int pl = ((4 + q) ^ r7r) * 8;
#pragma unroll
                for (int nt = 0; nt < 4; ++nt) {
                    const unsigned short* rb = cb + (wc + nt * 16 + s) * 64;
                    Wfh[nt] = *(bf16x8*)&rb[ph];
                    Wfl[nt] = *(bf16x8*)&rb[pl];
                }
            }

            // phase 4: A fragments from prefetched regs; issue A loads for it+1
            bf16x8 Afh[4], Afl[4];
#pragma unroll
            for (int mt = 0; mt < 4; ++mt) {
                uint4 uh, ul;
                cvt2(afc[mt * 2].x,     afc[mt * 2].y,     uh.x, ul.x);
                cvt2(afc[mt * 2].z,     afc[mt * 2].w,     uh.y, ul.y);
                cvt2(afc[mt * 2 + 1].x, afc[mt * 2 + 1].y, uh.z, ul.z);
                cvt2(afc[mt * 2 + 1].z, afc[mt * 2 + 1].w, uh.w, ul.w);
                Afh[mt] = __builtin_bit_cast(bf16x8, uh);
                Afl[mt] = __builtin_bit_cast(bf16x8, ul);
            }
            {
                const int kA = (it + 1 < 128) ? k0 + 32 : k0;
#pragma unroll
                for (int mt = 0; mt < 4; ++mt) {
                    afc[mt * 2]     = *(const float4*)(Arow + (size_t)mt * 16 * Dd + kA);
                    afc[mt * 2 + 1] = *(const float4*)(Arow + (size_t)mt * 16 * Dd + kA + 4);
                }
            }

            // phase 5: MFMA
#pragma unroll
            for (int mt = 0; mt < 4; ++mt)
#pragma unroll
                for (int nt = 0; nt < 4; ++nt) {
                    f32x4 a = acc[mt][nt];
                    a = MFMA16(Afl[mt], Wfh[nt], a);
                    a = MFMA16(Afh[mt], Wfl[nt], a);
                    a = MFMA16(Afh[mt], Wfh[nt], a);
                    acc[mt][nt] = a;
                }

            // phase 6: one barrier per step
            __syncthreads();
        }

#pragma unroll
        for (int nt = 0; nt < 4; ++nt) {
            float bv = bias[n0 + wc + nt * 16 + s];
#pragma unroll
            for (int mt = 0; mt < 4; ++mt)
#pragma unroll
                for (int r = 0; r < 4; ++r) {
                    int m = m0 + wr + mt * 16 + q * 4 + r;
                    C[(size_t)m * Dd + n0 + wc + nt * 16 + s] = fmaxf(acc[mt][nt][r] + bv, 0.f);
                }
        }
    }
}

// ---------------------------------------------------------------- gate: softmax(g @ gate_w + gb) + combine
// 4 batch rows per block (256 blocks): gate_w vectors loaded once, reused x4
// -> gate_w L2/L3 traffic 256MB -> 64MB.
__global__ __launch_bounds__(256) void gate_kernel(const float* __restrict__ g,
                                                   const float* __restrict__ gw,
                                                   const float* __restrict__ gb,
                                                   const float* __restrict__ eo,
                                                   float* __restrict__ out)
{
    int b0 = blockIdx.x * 4;
    int tid = threadIdx.x;
    int lane = tid & 63;
    int wv = tid >> 6;

    float acc[4][16];
#pragma unroll
    for (int bb = 0; bb < 4; ++bb)
#pragma unroll
        for (int j = 0; j < 16; ++j) acc[bb][j] = 0.f;

    const float* g0 = g + (size_t)b0 * Dd;
#pragma unroll
    for (int it = 0; it < Dd / 256; ++it) {
        int d = tid + it * 256;
        const float4* wr_ = (const float4*)(gw + (size_t)d * 16);
        float4 w0 = wr_[0], w1 = wr_[1], w2 = wr_[2], w3 = wr_[3];
        float gv[4];
#pragma unroll
        for (int bb = 0; bb < 4; ++bb) gv[bb] = g0[(size_t)bb * Dd + d];
#pragma unroll
        for (int bb = 0; bb < 4; ++bb) {
            float v = gv[bb];
            acc[bb][0]  += v * w0.x;  acc[bb][1]  += v * w0.y;
            acc[bb][2]  += v * w0.z;  acc[bb][3]  += v * w0.w;
            acc[bb][4]  += v * w1.x;  acc[bb][5]  += v * w1.y;
            acc[bb][6]  += v * w1.z;  acc[bb][7]  += v * w1.w;
            acc[bb][8]  += v * w2.x;  acc[bb][9]  += v * w2.y;
            acc[bb][10] += v * w2.z;  acc[bb][11] += v * w2.w;
            acc[bb][12] += v * w3.x;  acc[bb][13] += v * w3.y;
            acc[bb][14] += v * w3.z;  acc[bb][15] += v * w3.w;
        }
    }

    __shared__ float red[4][4][16];     // [wave][bb][j]
    __shared__ float logits[4][16];
#pragma unroll
    for (int bb = 0; bb < 4; ++bb)
#pragma unroll
        for (int j = 0; j < 16; ++j) {
            float v = acc[bb][j];
#pragma unroll
            for (int m = 32; m >= 1; m >>= 1) v += __shfl_xor(v, m);
            if (lane == 0) red[wv][bb][j] = v;
        }
    __syncthreads();
    if (tid < 64) {
        int bb = tid >> 4, j = tid & 15;
        logits[bb][j] = gb[j] + red[0][bb][j] + red[1][bb][j] + red[2][bb][j] + red[3][bb][j];
    }
    __syncthreads();
    if (tid < 4) {
        int b = b0 + tid;
        float m = logits[tid][0];
#pragma unroll
        for (int j = 1; j < 16; ++j) m = fmaxf(m, logits[tid][j]);
        float ex[16], ssum = 0.f;
#pragma unroll
        for (int j = 0; j < 16; ++j) { ex[j] = __expf(logits[tid][j] - m); ssum += ex[j]; }
        float inv = 1.f / ssum;
        float o = 0.f;
#pragma unroll
        for (int j = 0; j < 16; ++j) o += ex[j] * inv * eo[(size_t)j * Bsz + b];
        out[b] = o;
    }
}

// ----------------------------------------------------------------
extern "C" void kernel_launch(void* const* d_in, const int* in_sizes, int n_in,
                              void* d_out, int out_size, void* d_ws, size_t ws_size,
                              hipStream_t stream)
{
    const float* x     = (const float*)d_in[0];
    const float* gamma = (const float*)d_in[1];
    const float* beta  = (const float*)d_in[2];
    const float* mean  = (const float*)d_in[3];
    const float* var   = (const float*)d_in[4];
    const float* k1    = (const float*)d_in[5];
    const float* r1    = (const float*)d_in[6];
    const float* b1    = (const float*)d_in[7];
    const float* k2    = (const float*)d_in[8];
    const float* r2    = (const float*)d_in[9];
    const float* b2    = (const float*)d_in[10];
    const float* dw    = (const float*)d_in[11];
    const float* db    = (const float*)d_in[12];
    const float* fc1w  = (const float*)d_in[13];
    const float* fc1b  = (const float*)d_in[14];
    const float* gw    = (const float*)d_in[15];
    const float* gb    = (const float*)d_in[16];
    float* out = (float*)d_out;

    // workspace: 33.1 MB (<= previously-proven 34.2 MB footprint)
    float* g = (float*)d_ws;                                        // 4,194,304 f (16 MB)
    unsigned short* xph = (unsigned short*)(g + (size_t)Bsz * Dd);  // 8 MB
    unsigned short* xpl = xph + (size_t)Bsz * Dd / 2 * 2;           // 8 MB
    float* pw  = (float*)(xpl + (size_t)4194304);                   // 120,320 f
    float* eo  = pw + (size_t)Ee * PWE;                             // 16,384 f

    xpack_kernel<<<2048, 256, 0, stream>>>(x, gamma, beta, mean, var, xph, xpl);
    repack2_kernel<<<(Ee * PWE + 255) / 256, 256, 0, stream>>>(k1, r1, b1, k2, r2, b2, pw);
    fused_kernel<<<512, 256, 0, stream>>>(xph, xpl, pw, dw, db, eo, x, fc1w, fc1b, g);
    gate_kernel<<<Bsz / 4, 256, 0, stream>>>(g, gw, gb, eo, out);
}

// Round 9
// 401.489 us; speedup vs baseline: 2.2118x; 1.1208x over previous
//
#include <hip/hip_runtime.h>
#include <math.h>

#define Bsz 1024
#define Tt  128
#define Ff  32
#define Ee  16
#define Hh  20
#define Dd  4096
#define EPSc 1e-3f
#define LOG2E 1.4426950408889634f

// repacked fp32 weights per expert, gate-interleaved cols c = 4*u + g (g: i,f,g,o):
// K1p[32][80]@0, R1p[20][80]@2560, K2p[20][80]@4160, R2p[20][80]@5760,
// b1p[80]@7360, b2p[80]@7440  -> 7520 floats per expert
// i/f/o gate columns (g != 2) are pre-scaled by log2(e) so sigmoid uses exp2 directly.
#define PWE 7520

typedef __attribute__((ext_vector_type(8))) short bf16x8;
typedef __attribute__((ext_vector_type(4))) float f32x4;
typedef __attribute__((ext_vector_type(4))) unsigned int u32x4;

#define MFMA16(a,b,c) __builtin_amdgcn_mfma_f32_16x16x32_bf16(a, b, c, 0, 0, 0)

__device__ __forceinline__ float sig2(float z) {      // z already scaled by log2(e)
    return __builtin_amdgcn_rcpf(1.0f + __builtin_amdgcn_exp2f(-z));
}
__device__ __forceinline__ unsigned short bf16_rne(float f) {
    unsigned u = __float_as_uint(f);
    u += 0x7FFFu + ((u >> 16) & 1u);
    return (unsigned short)(u >> 16);
}
__device__ __forceinline__ float bf16_to_f(unsigned short h) {
    return __uint_as_float(((unsigned)h) << 16);
}
// split 2 floats into packed-bf16 hi word + packed-bf16 lo word, RNE both
// (identical numerics to bf16_rne path; v_cvt_pk_bf16_f32 is RNE).
__device__ __forceinline__ void cvt2(float f0, float f1, unsigned& hp, unsigned& lp) {
    asm("v_cvt_pk_bf16_f32 %0, %1, %2" : "=v"(hp) : "v"(f0), "v"(f1));
    float h0 = __uint_as_float(hp << 16);
    float h1 = __uint_as_float(hp & 0xFFFF0000u);
    asm("v_cvt_pk_bf16_f32 %0, %1, %2" : "=v"(lp) : "v"(f0 - h0), "v"(f1 - h1));
}

// ---------------------------------------------------------------- prep: xpack (blocks 0..2047) + weight repack (2048..)
__global__ void prep_kernel(const float* __restrict__ x,
                            const float* __restrict__ gamma, const float* __restrict__ beta,
                            const float* __restrict__ mean,  const float* __restrict__ var,
                            unsigned short* __restrict__ xph, unsigned short* __restrict__ xpl,
                            const float* __restrict__ k1, const float* __restrict__ r1,
                            const float* __restrict__ b1, const float* __restrict__ k2,
                            const float* __restrict__ r2, const float* __restrict__ b2,
                            float* __restrict__ pw)
{
    int tid = threadIdx.x;
    if (blockIdx.x < 2048) {
        // ---- xpack: BN + bf16 hi/lo split into per-(chunk,t,lane) fragment layout
        __shared__ float sc[Ff], sh[Ff];
        if (tid < Ff) {
            float s = gamma[tid] * rsqrtf(var[tid] + EPSc);
            sc[tid] = s;
            sh[tid] = beta[tid] - mean[tid] * s;
        }
        __syncthreads();
        int idx = blockIdx.x * 256 + tid;           // 0 .. 64*128*64-1
        int c   = idx >> 13;
        int rem = idx & 8191;
        int t   = rem >> 6;
        int l   = rem & 63;
        int q   = l >> 4, s = l & 15;
        const float* xr = x + ((size_t)(c * 16 + s) * Tt + t) * Ff + q * 8;
        float4 v0 = *(const float4*)xr;
        float4 v1 = *(const float4*)(xr + 4);
        float xv[8] = {v0.x, v0.y, v0.z, v0.w, v1.x, v1.y, v1.z, v1.w};
        bf16x8 hv, lv;
#pragma unroll
        for (int j = 0; j < 8; ++j) {
            int f = q * 8 + j;
            float xn_ = xv[j] * sc[f] + sh[f];
            unsigned short hi = bf16_rne(xn_);
            hv[j] = (short)hi;
            lv[j] = (short)bf16_rne(xn_ - bf16_to_f(hi));
        }
        *(bf16x8*)(xph + (size_t)idx * 8) = hv;
        *(bf16x8*)(xpl + (size_t)idx * 8) = lv;
    } else {
        // ---- weight repack (gate-interleave)
        int idx = (blockIdx.x - 2048) * 256 + tid;
        if (idx >= Ee * PWE) return;
        int e = idx / PWE;
        int o = idx % PWE;
        float v;
        int g;
        if (o < 7360) {
            int c = o % 80, u = c >> 2;
            g = c & 3;
            int co = g * 20 + u;
            if (o < 2560) {
                int kk = o / 80;
                v = k1[((size_t)e * Ff + kk) * 80 + co];
            } else if (o < 4160) {
                int kk = (o - 2560) / 80;
                v = r1[((size_t)e * Hh + kk) * 80 + co];
            } else if (o < 5760) {
                int kk = (o - 4160) / 80;
                v = k2[((size_t)e * Hh + kk) * 80 + co];
            } else {
                int kk = (o - 5760) / 80;
                v = r2[((size_t)e * Hh + kk) * 80 + co];
            }
        } else if (o < 7440) {
            int c = o - 7360, u = c >> 2;
            g = c & 3;
            v = b1[(size_t)e * 80 + g * 20 + u];
        } else {
            int c = o - 7440, u = c >> 2;
            g = c & 3;
            v = b2[(size_t)e * 80 + g * 20 + u];
        }
        if (g != 2) v *= LOG2E;     // sigmoid gates -> exp2 domain
        pw[idx] = v;
    }
}

// ---------------------------------------------------------------- fused lstm + fc1
// 512 blocks x 256 thr, 2 blocks/CU. Blocks i and i+256 land on the same CU; selector
// blockIdx.x<256 pairs 1 LSTM block + 1 fc1 block per CU (m114 co-scheduling).
//
// LSTM: swapped-operand MFMA + permuted k-map; h fully register-resident (no LDS).
// fc1: 128x128 tile. BOTH operands staged through double-buffered LDS (64KB total):
//   W: 16 coalesced 256B row-loads/thread-step, cvt2 at stage (R8 geometry).
//   A: cooperative coalesced tile load -- thread t reads row (t>>3)+32p, 16B at col
//      4*(t&7): 8 lanes cover one 128B row-segment -> 32 segments/wave/step (vs ~128
//      scattered 16B txns for the old per-lane direct loads). cvt2 at stage time
//      (8 cvt2/thread, was 16 at consumer). Rows are 64 shorts = 8 x 16B slots,
//      XOR slot swizzle phys = lslot ^ (row&7) (R8-proven, 16B-aligned, conflict-free).
// Prefetch is 2-DEEP via loop unroll x2 with NAMED even/odd reg buffers wA/aA, wB/aB
// (static indexing, rule #20) -> load->stage gap = 2 k-steps (~1000+cy > HBM 900cy).
// One barrier per k-step (2 per unrolled iter).
__global__ __launch_bounds__(256, 2) void fused_kernel(
    const unsigned short* __restrict__ xph, const unsigned short* __restrict__ xpl,
    const float* __restrict__ pw, const float* __restrict__ dw, const float* __restrict__ db,
    float* __restrict__ eo,
    const float* __restrict__ x, const float* __restrict__ W,
    const float* __restrict__ bias, float* __restrict__ C)
{
    __shared__ __align__(16) char smem[65536];   // 2 bufs x (W 16KB + A 16KB)

    if (blockIdx.x < 256) {
        // ================= LSTM path: wave w handles tile blockIdx.x*4+w =================
        const int l = threadIdx.x & 63;
        const int q = l >> 4, s = l & 15;
        const int tile = (blockIdx.x << 2) + (threadIdx.x >> 6);
        const int e = tile >> 6;
        const int c = tile & 63;
        const int b0 = c * 16;

        const float* Wm = pw + (size_t)e * PWE;
        bf16x8 K1h[5], K1l[5], R1h[5], R1l[5], K2h[5], K2l[5], R2h[5], R2l[5];
#pragma unroll
        for (int n = 0; n < 5; ++n) {
#pragma unroll
            for (int j = 0; j < 8; ++j) {
                int k8 = q * 8 + j;         // K1: x-feature k-map (32 features)
                int uk = 4 * j + q;         // R1/K2/R2: permuted h-unit k-map (j<5 valid)
                int cc = n * 16 + s;
                float wv_;
                unsigned short hi; float hf;
                wv_ = Wm[k8 * 80 + cc];
                hi = bf16_rne(wv_); hf = bf16_to_f(hi);
                K1h[n][j] = (short)hi; K1l[n][j] = (short)bf16_rne(wv_ - hf);
                wv_ = (j < 5) ? Wm[2560 + uk * 80 + cc] : 0.f;
                hi = bf16_rne(wv_); hf = bf16_to_f(hi);
                R1h[n][j] = (short)hi; R1l[n][j] = (short)bf16_rne(wv_ - hf);
                wv_ = (j < 5) ? Wm[4160 + uk * 80 + cc] : 0.f;
                hi = bf16_rne(wv_); hf = bf16_to_f(hi);
                K2h[n][j] = (short)hi; K2l[n][j] = (short)bf16_rne(wv_ - hf);
                wv_ = (j < 5) ? Wm[5760 + uk * 80 + cc] : 0.f;
                hi = bf16_rne(wv_); hf = bf16_to_f(hi);
                R2h[n][j] = (short)hi; R2l[n][j] = (short)bf16_rne(wv_ - hf);
            }
        }
        f32x4 bf1[5], bf2[5];
        float dwr[5];
#pragma unroll
        for (int n = 0; n < 5; ++n) {
            bf1[n] = *(const f32x4*)&Wm[7360 + n * 16 + 4 * q];
            bf2[n] = *(const f32x4*)&Wm[7440 + n * 16 + 4 * q];
            dwr[n] = dw[e * Hh + 4 * n + q];
        }

        float c1[5] = {0, 0, 0, 0, 0}, c2[5] = {0, 0, 0, 0, 0};
        float h2reg[5] = {0, 0, 0, 0, 0};

        const bf16x8 z8 = {0, 0, 0, 0, 0, 0, 0, 0};
        bf16x8 H1a = z8, H1b = z8, H2a = z8, H2b = z8;   // h[t-1] fragments, reg-resident

        const unsigned short* xbh = xph + (size_t)c * 65536 + l * 8;
        const unsigned short* xbl = xpl + (size_t)c * 65536 + l * 8;
        bf16x8 xch = *(const bf16x8*)xbh;
        bf16x8 xcl = *(const bf16x8*)xbl;

#pragma unroll 1
        for (int t = 0; t < Tt; ++t) {
            bf16x8 xnh = xch, xnl = xcl;
            if (t < Tt - 1) {       // prefetch t+1 (overlaps this step's compute)
                xnh = *(const bf16x8*)(xbh + (t + 1) * 512);
                xnl = *(const bf16x8*)(xbl + (t + 1) * 512);
            }

            // ---- layer 1: z^T = K1^T x^T + R1^T h1^T  (x first, fresh H1 last)
            f32x4 a1[5];
#pragma unroll
            for (int n = 0; n < 5; ++n) {
                f32x4 acc = bf1[n];
                acc = MFMA16(K1h[n], xch, acc);
                acc = MFMA16(K1l[n], xch, acc);
                acc = MFMA16(K1h[n], xcl, acc);
                acc = MFMA16(R1h[n], H1a, acc);
                acc = MFMA16(R1l[n], H1a, acc);
                acc = MFMA16(R1h[n], H1b, acc);
                a1[n] = acc;
            }
            {
                float hv[5];
#pragma unroll
                for (int n = 0; n < 5; ++n) {
                    float iv = sig2(a1[n][0]);
                    float fv = sig2(a1[n][1]);
                    float gv = fmaxf(a1[n][2], 0.f);
                    float ov = sig2(a1[n][3]);
                    c1[n] = fv * c1[n] + iv * gv;
                    hv[n] = ov * fmaxf(c1[n], 0.f);
                }
                unsigned h0, h1, h2, l0, l1, l2;
                cvt2(hv[0], hv[1], h0, l0);
                cvt2(hv[2], hv[3], h1, l1);
                cvt2(hv[4], 0.f,   h2, l2);
                u32x4 uh = {h0, h1, h2, 0u}, ul = {l0, l1, l2, 0u};
                H1a = __builtin_bit_cast(bf16x8, uh);
                H1b = __builtin_bit_cast(bf16x8, ul);
            }

            // ---- layer 2: stale H2 first, freshly-packed H1 last (cvt2 slack)
            f32x4 a2[5];
#pragma unroll
            for (int n = 0; n < 5; ++n) {
                f32x4 acc = bf2[n];
                acc = MFMA16(R2h[n], H2a, acc);
                acc = MFMA16(R2l[n], H2a, acc);
                acc = MFMA16(R2h[n], H2b, acc);
                acc = MFMA16(K2h[n], H1a, acc);
                acc = MFMA16(K2l[n], H1a, acc);
                acc = MFMA16(K2h[n], H1b, acc);
                a2[n] = acc;
            }
            {
                float hv[5];
#pragma unroll
                for (int n = 0; n < 5; ++n) {
                    float iv = sig2(a2[n][0]);
                    float fv = sig2(a2[n][1]);
                    float gv = fmaxf(a2[n][2], 0.f);
                    float ov = sig2(a2[n][3]);
                    c2[n] = fv * c2[n] + iv * gv;
                    float h = ov * fmaxf(c2[n], 0.f);
                    h2reg[n] = h;
                    hv[n] = h;
                }
                unsigned h0, h1, h2, l0, l1, l2;
                cvt2(hv[0], hv[1], h0, l0);
                cvt2(hv[2], hv[3], h1, l1);
                cvt2(hv[4], 0.f,   h2, l2);
                u32x4 uh = {h0, h1, h2, 0u}, ul = {l0, l1, l2, 0u};
                H2a = __builtin_bit_cast(bf16x8, uh);
                H2b = __builtin_bit_cast(bf16x8, ul);
            }

            xch = xnh; xcl = xnl;
        }

        float p = 0.f;
#pragma unroll
        for (int n = 0; n < 5; ++n) p += h2reg[n] * dwr[n];
        p += __shfl_xor(p, 16);
        p += __shfl_xor(p, 32);
        if (q == 0) eo[(size_t)e * Bsz + b0 + s] = db[e] + p;

    } else {
        // ================= fc1 path: 128x128, W+A staged, 2-deep prefetch =================
        const int tid = threadIdx.x;
        const int wv = tid >> 6, l = tid & 63, q = l >> 4, s = l & 15;
        const int id = blockIdx.x & 255;
        const int n0 = (id & 31) * 128, m0 = (id >> 5) * 128;
        const int wr = (wv & 1) * 64, wc = (wv >> 1) * 64;

        // W stage mapping (R8 geometry)
        const int wn = tid & 127, wkq = tid >> 7;
        const int r7w = wn & 7;
        const int pw0 = ((2 * wkq)     ^ r7w) * 8;
        const int pw1 = ((2 * wkq + 1) ^ r7w) * 8;
        const int pw2 = ((4 + 2 * wkq) ^ r7w) * 8;
        const int pw3 = ((5 + 2 * wkq) ^ r7w) * 8;
        const float* WG = W + (size_t)(wkq * 16) * Dd + n0 + wn;

        // A stage mapping: thread t loads rows (t>>3)+32p, float4 at col 4*(t&7)
        const int ar = tid >> 3, ac = tid & 7;
        const int akc = ac >> 1, ahalf = ac & 1;
        const int pa_h = ((akc       ^ (ar & 7)) << 3) + ahalf * 4;  // short offsets in row
        const int pa_l = (((4 + akc) ^ (ar & 7)) << 3) + ahalf * 4;
        const float* AG = x + (size_t)(m0 + ar) * Dd + 4 * ac;

        // fragment read offsets (same for W and A rows)
        const int r7r = s & 7;
        const int pfh = (q ^ r7r) * 8;
        const int pfl = ((4 + q) ^ r7r) * 8;

        unsigned short* lds = (unsigned short*)smem;   // buf0 @0, buf1 @16384 shorts
        unsigned short* c0 = lds;                      // even k-steps
        unsigned short* c1 = lds + 16384;              // odd k-steps

        f32x4 acc[4][4];
#pragma unroll
        for (int mt = 0; mt < 4; ++mt)
#pragma unroll
            for (int nt = 0; nt < 4; ++nt) acc[mt][nt] = (f32x4){0.f, 0.f, 0.f, 0.f};

        float wA[16], wB[16];
        float4 aA[4], aB[4];

#define LOADW(dst, kk)                                                     \
        {                                                                  \
            const int kw_ = (kk);                                          \
            _Pragma("unroll")                                              \
            for (int i_ = 0; i_ < 16; ++i_)                                \
                dst[i_] = WG[(size_t)(kw_ + i_) * Dd];                     \
        }
#define LOADA(dst, kk)                                                     \
        {                                                                  \
            const int ka_ = (kk);                                          \
            _Pragma("unroll")                                              \
            for (int p_ = 0; p_ < 4; ++p_)                                 \
                dst[p_] = *(const float4*)(AG + (size_t)(32 * p_) * Dd + ka_); \
        }
#define STAGEW(dst, src)                                                   \
        {                                                                  \
            uint4 h0, l0, h1, l1;                                          \
            cvt2(src[0],  src[1],  h0.x, l0.x); cvt2(src[2],  src[3],  h0.y, l0.y); \
            cvt2(src[4],  src[5],  h0.z, l0.z); cvt2(src[6],  src[7],  h0.w, l0.w); \
            cvt2(src[8],  src[9],  h1.x, l1.x); cvt2(src[10], src[11], h1.y, l1.y); \
            cvt2(src[12], src[13], h1.z, l1.z); cvt2(src[14], src[15], h1.w, l1.w); \
            unsigned short* rb_ = (dst) + wn * 64;                         \
            *(uint4*)&rb_[pw0] = h0;                                       \
            *(uint4*)&rb_[pw1] = h1;                                       \
            *(uint4*)&rb_[pw2] = l0;                                       \
            *(uint4*)&rb_[pw3] = l1;                                       \
        }
#define STAGEA(dst, src)                                                   \
        {                                                                  \
            _Pragma("unroll")                                              \
            for (int p_ = 0; p_ < 4; ++p_) {                               \
                unsigned h0_, l0_, h1_, l1_;                               \
                cvt2(src[p_].x, src[p_].y, h0_, l0_);                      \
                cvt2(src[p_].z, src[p_].w, h1_, l1_);                      \
                unsigned short* rb_ = (dst) + 8192 + (ar + 32 * p_) * 64;  \
                uint2 hv_ = {h0_, h1_}, lv_ = {l0_, l1_};                  \
                *(uint2*)&rb_[pa_h] = hv_;                                 \
                *(uint2*)&rb_[pa_l] = lv_;                                 \
            }                                                              \
        }
#define COMPUTE(cb)                                                        \
        {                                                                  \
            bf16x8 Wfh[4], Wfl[4], Afh[4], Afl[4];                         \
            _Pragma("unroll")                                              \
            for (int nt = 0; nt < 4; ++nt) {                               \
                const unsigned short* rb_ = (cb) + (wc + nt * 16 + s) * 64; \
                Wfh[nt] = *(bf16x8*)&rb_[pfh];                             \
                Wfl[nt] = *(bf16x8*)&rb_[pfl];                             \
            }                                                              \
            _Pragma("unroll")                                              \
            for (int mt = 0; mt < 4; ++mt) {                               \
                const unsigned short* ra_ = (cb) + 8192 + (wr + mt * 16 + s) * 64; \
                Afh[mt] = *(bf16x8*)&ra_[pfh];                             \
                Afl[mt] = *(bf16x8*)&ra_[pfl];                             \
            }                                                              \
            _Pragma("unroll")                                              \
            for (int mt = 0; mt < 4; ++mt)                                 \
                _Pragma("unroll")                                          \
                for (int nt = 0; nt < 4; ++nt) {                           \
                    f32x4 a_ = acc[mt][nt];                                \
                    a_ = MFMA16(Afl[mt], Wfh[nt], a_);                     \
                    a_ = MFMA16(Afh[mt], Wfl[nt], a_);                     \
                    a_ = MFMA16(Afh[mt], Wfh[nt], a_);                     \
                    acc[mt][nt] = a_;                                      \
                }                                                          \
        }

        {   // prologue: stage step0 -> buf0; load step1 -> A-bufs, step2 -> B-bufs
            float w0[16]; float4 a0[4];
            LOADW(w0, 0); LOADA(a0, 0);
            STAGEW(c0, w0); STAGEA(c0, a0);
            LOADW(wA, 32); LOADA(aA, 32);
            LOADW(wB, 64); LOADA(aB, 64);
            __syncthreads();
        }

#pragma unroll 1
        for (int it = 0; it < 128; it += 2) {
            // even half: compute step it (buf0); stage step it+1 -> buf1; load it+3
            STAGEW(c1, wA); STAGEA(c1, aA);
            {
                const int kk = (it + 3 < 128) ? (it + 3) * 32 : 0;
                LOADW(wA, kk); LOADA(aA, kk);
            }
            COMPUTE(c0);
            __syncthreads();

            // odd half: compute step it+1 (buf1); stage step it+2 -> buf0; load it+4
            if (it + 2 < 128) { STAGEW(c0, wB); STAGEA(c0, aB); }
            {
                const int kk = (it + 4 < 128) ? (it + 4) * 32 : 0;
                LOADW(wB, kk); LOADA(aB, kk);
            }
            COMPUTE(c1);
            __syncthreads();
        }
#undef LOADW
#undef LOADA
#undef STAGEW
#undef STAGEA
#undef COMPUTE

#pragma unroll
        for (int nt = 0; nt < 4; ++nt) {
            float bv = bias[n0 + wc + nt * 16 + s];
#pragma unroll
            for (int mt = 0; mt < 4; ++mt)
#pragma unroll
                for (int r = 0; r < 4; ++r) {
                    int m = m0 + wr + mt * 16 + q * 4 + r;
                    C[(size_t)m * Dd + n0 + wc + nt * 16 + s] = fmaxf(acc[mt][nt][r] + bv, 0.f);
                }
        }
    }
}

// ---------------------------------------------------------------- gate: softmax(g @ gate_w + gb) + combine
// 4 batch rows per block (256 blocks): gate_w vectors loaded once, reused x4
// -> gate_w L2/L3 traffic 256MB -> 64MB.
__global__ __launch_bounds__(256) void gate_kernel(const float* __restrict__ g,
                                                   const float* __restrict__ gw,
                                                   const float* __restrict__ gb,
                                                   const float* __restrict__ eo,
                                                   float* __restrict__ out)
{
    int b0 = blockIdx.x * 4;
    int tid = threadIdx.x;
    int lane = tid & 63;
    int wv = tid >> 6;

    float acc[4][16];
#pragma unroll
    for (int bb = 0; bb < 4; ++bb)
#pragma unroll
        for (int j = 0; j < 16; ++j) acc[bb][j] = 0.f;

    const float* g0 = g + (size_t)b0 * Dd;
#pragma unroll
    for (int it = 0; it < Dd / 256; ++it) {
        int d = tid + it * 256;
        const float4* wr_ = (const float4*)(gw + (size_t)d * 16);
        float4 w0 = wr_[0], w1 = wr_[1], w2 = wr_[2], w3 = wr_[3];
        float gv[4];
#pragma unroll
        for (int bb = 0; bb < 4; ++bb) gv[bb] = g0[(size_t)bb * Dd + d];
#pragma unroll
        for (int bb = 0; bb < 4; ++bb) {
            float v = gv[bb];
            acc[bb][0]  += v * w0.x;  acc[bb][1]  += v * w0.y;
            acc[bb][2]  += v * w0.z;  acc[bb][3]  += v * w0.w;
            acc[bb][4]  += v * w1.x;  acc[bb][5]  += v * w1.y;
            acc[bb][6]  += v * w1.z;  acc[bb][7]  += v * w1.w;
            acc[bb][8]  += v * w2.x;  acc[bb][9]  += v * w2.y;
            acc[bb][10] += v * w2.z;  acc[bb][11] += v * w2.w;
            acc[bb][12] += v * w3.x;  acc[bb][13] += v * w3.y;
            acc[bb][14] += v * w3.z;  acc[bb][15] += v * w3.w;
        }
    }

    __shared__ float red[4][4][16];     // [wave][bb][j]
    __shared__ float logits[4][16];
#pragma unroll
    for (int bb = 0; bb < 4; ++bb)
#pragma unroll
        for (int j = 0; j < 16; ++j) {
            float v = acc[bb][j];
#pragma unroll
            for (int m = 32; m >= 1; m >>= 1) v += __shfl_xor(v, m);
            if (lane == 0) red[wv][bb][j] = v;
        }
    __syncthreads();
    if (tid < 64) {
        int bb = tid >> 4, j = tid & 15;
        logits[bb][j] = gb[j] + red[0][bb][j] + red[1][bb][j] + red[2][bb][j] + red[3][bb][j];
    }
    __syncthreads();
    if (tid < 4) {
        int b = b0 + tid;
        float m = logits[tid][0];
#pragma unroll
        for (int j = 1; j < 16; ++j) m = fmaxf(m, logits[tid][j]);
        float ex[16], ssum = 0.f;
#pragma unroll
        for (int j = 0; j < 16; ++j) { ex[j] = __expf(logits[tid][j] - m); ssum += ex[j]; }
        float inv = 1.f / ssum;
        float o = 0.f;
#pragma unroll
        for (int j = 0; j < 16; ++j) o += ex[j] * inv * eo[(size_t)j * Bsz + b];
        out[b] = o;
    }
}

// ----------------------------------------------------------------
extern "C" void kernel_launch(void* const* d_in, const int* in_sizes, int n_in,
                              void* d_out, int out_size, void* d_ws, size_t ws_size,
                              hipStream_t stream)
{
    const float* x     = (const float*)d_in[0];
    const float* gamma = (const float*)d_in[1];
    const float* beta  = (const float*)d_in[2];
    const float* mean  = (const float*)d_in[3];
    const float* var   = (const float*)d_in[4];
    const float* k1    = (const float*)d_in[5];
    const float* r1    = (const float*)d_in[6];
    const float* b1    = (const float*)d_in[7];
    const float* k2    = (const float*)d_in[8];
    const float* r2    = (const float*)d_in[9];
    const float* b2    = (const float*)d_in[10];
    const float* dw    = (const float*)d_in[11];
    const float* db    = (const float*)d_in[12];
    const float* fc1w  = (const float*)d_in[13];
    const float* fc1b  = (const float*)d_in[14];
    const float* gw    = (const float*)d_in[15];
    const float* gb    = (const float*)d_in[16];
    float* out = (float*)d_out;

    // workspace: 33.1 MB (<= previously-proven 34.2 MB footprint)
    float* g = (float*)d_ws;                                        // 4,194,304 f (16 MB)
    unsigned short* xph = (unsigned short*)(g + (size_t)Bsz * Dd);  // 8 MB
    unsigned short* xpl = xph + (size_t)Bsz * Dd / 2 * 2;           // 8 MB
    float* pw  = (float*)(xpl + (size_t)4194304);                   // 120,320 f
    float* eo  = pw + (size_t)Ee * PWE;                             // 16,384 f

    prep_kernel<<<2048 + (Ee * PWE + 255) / 256, 256, 0, stream>>>(
        x, gamma, beta, mean, var, xph, xpl, k1, r1, b1, k2, r2, b2, pw);
    fused_kernel<<<512, 256, 0, stream>>>(xph, xpl, pw, dw, db, eo, x, fc1w, fc1b, g);
    gate_kernel<<<Bsz / 4, 256, 0, stream>>>(g, gw, gb, eo, out);
}